// Round 13
// baseline (363.587 us; speedup 1.0000x reference)
//
#include <hip/hip_runtime.h>
#include <hip/hip_bf16.h>
#include <stdint.h>

#define LDIM 512
#define CDIM 128
#define NPOS (LDIM*LDIM)   // 262144 positions

typedef __attribute__((ext_vector_type(8))) short bf16x8;
typedef __attribute__((ext_vector_type(4))) float f32x4;

__device__ __forceinline__ unsigned short f2bf(float f) {
  union { __hip_bfloat16 h; unsigned short u; } cv;
  cv.h = __float2bfloat16(f);
  return cv.u;
}

__device__ __forceinline__ float bf2f(unsigned short u) {
  union { unsigned int i; float f; } cv; cv.i = ((unsigned int)u) << 16; return cv.f;
}

__device__ __forceinline__ float sigm(float x) { return 1.0f / (1.0f + __expf(-x)); }

// async global->LDS, 16B per lane. LDS dest must be wave-uniform; HW adds lane*16.
__device__ __forceinline__ void gl_lds16(const unsigned short* g, unsigned short* l) {
  __builtin_amdgcn_global_load_lds(
      (const __attribute__((address_space(1))) unsigned int*)g,
      (__attribute__((address_space(3))) unsigned int*)l, 16, 0, 0);
}

// ---------------------------------------------------------------------------
// K0: transpose + convert 6 weight matrices (128x128 f32 [k][n]) into
// bf16 Wt[n][k], pre-swizzled: 16B chunk s stored at slot (s ^ (n&7)).
// Slots: 0=w_left 1=w_lgate 2=w_right 3=w_rgate 4=w_out 5=w_fgate
// ---------------------------------------------------------------------------
__global__ __launch_bounds__(256) void k_prep(
    const float* w0, const float* w1, const float* w2,
    const float* w3, const float* w4, const float* w5,
    unsigned short* wtall) {
  __shared__ float tmp[CDIM*CDIM];   // 64KB
  const float* w = (blockIdx.x==0)?w0:(blockIdx.x==1)?w1:(blockIdx.x==2)?w2:
                   (blockIdx.x==3)?w3:(blockIdx.x==4)?w4:w5;
  int t = threadIdx.x;
  #pragma unroll
  for (int m = 0; m < 16; ++m)
    ((float4*)tmp)[m*256 + t] = ((const float4*)w)[m*256 + t];
  __syncthreads();
  unsigned short* out = wtall + (size_t)blockIdx.x * (CDIM*CDIM);
  #pragma unroll
  for (int m = 0; m < 8; ++m) {
    int oc = m*256 + t;            // output 16B chunk index (n*16 + sc)
    int n = oc >> 4, sc = oc & 15;
    int s = sc ^ (n & 7);          // data chunk that lands in slot sc
    union { unsigned short u[8]; uint4 v; } pk;
    #pragma unroll
    for (int e = 0; e < 8; ++e) pk.u[e] = f2bf(tmp[(s*8 + e)*CDIM + n]);
    *(uint4*)(out + (size_t)oc*8) = pk.v;
  }
}

// ---------------------------------------------------------------------------
// K_LN: pure streaming LayerNorm. act (f32 [pos][128]) -> xbf (bf16, chunk-
// swizzled: data chunk ch of row pos stored at slot ch^(pos&7)).
// Lane qq owns chunks {qq, 4+qq, 8+qq, 12+qq} -> full-line stores.
// ---------------------------------------------------------------------------
__global__ __launch_bounds__(256,8) void k_ln(
    const float* __restrict__ act,
    const float* __restrict__ nscale, const float* __restrict__ nbias,
    unsigned short* __restrict__ xbf) {
  const int t = threadIdx.x;
  const int pos = blockIdx.x * 64 + (t >> 2), qq = t & 3;
  const int s = pos & 7;

  float4 av[8];
  const float4* ap = (const float4*)(act + (size_t)pos*CDIM);
  #pragma unroll
  for (int cc = 0; cc < 4; ++cc) {
    int ch = cc*4 + qq;
    av[cc*2]     = ap[ch*2];
    av[cc*2 + 1] = ap[ch*2 + 1];
  }

  float sm = 0.f, s2 = 0.f;
  #pragma unroll
  for (int j = 0; j < 8; ++j) {
    float4 v = av[j];
    sm += v.x + v.y + v.z + v.w;
    s2 += v.x*v.x + v.y*v.y + v.z*v.z + v.w*v.w;
  }
  sm += __shfl_xor(sm, 1); s2 += __shfl_xor(s2, 1);
  sm += __shfl_xor(sm, 2); s2 += __shfl_xor(s2, 2);
  float mu = sm * 0.0078125f;
  float rs = rsqrtf(fmaxf(s2 * 0.0078125f - mu*mu, 0.f) + 1e-5f);

  unsigned short* xp = xbf + (size_t)pos * CDIM;
  #pragma unroll
  for (int cc = 0; cc < 4; ++cc) {
    int ch = cc*4 + qq;
    union { unsigned short u[8]; uint4 v; } pk;
    #pragma unroll
    for (int e2 = 0; e2 < 2; ++e2) {
      float4 v = av[cc*2 + e2];
      float4 fs = ((const float4*)nscale)[ch*2 + e2];
      float4 fb = ((const float4*)nbias)[ch*2 + e2];
      int b = e2*4;
      pk.u[b+0] = f2bf((v.x - mu)*rs*fs.x + fb.x);
      pk.u[b+1] = f2bf((v.y - mu)*rs*fs.y + fb.y);
      pk.u[b+2] = f2bf((v.z - mu)*rs*fs.z + fb.z);
      pk.u[b+3] = f2bf((v.w - mu)*rs*fs.w + fb.w);
    }
    int slot = ch ^ s;
    *(uint4*)(xp + slot*8) = pk.v;
  }
}

// ---------------------------------------------------------------------------
// K_PROJ v6: R7 relay/2-barrier structure + value-weights-in-registers ->
// LDS = gate 32KB + xs 16KB = 48KB -> 3 blocks/CU (24 waves, 75% occ target).
// 8 waves = 2 row-groups (32 rows) x 4 col-groups (32 cols). 64-pos tiles
// (128B/plane/tile store coverage -> no RMW). launch_bounds(512,6): VGPR<=85.
// ---------------------------------------------------------------------------
__global__ __launch_bounds__(512,6) void k_proj(
    const unsigned short* __restrict__ xbf,
    const float* __restrict__ mask,
    const float* __restrict__ b_left, const float* __restrict__ b_lgate,
    const float* __restrict__ b_right, const float* __restrict__ b_rgate,
    const unsigned short* __restrict__ wtall,
    unsigned short* __restrict__ leftT,
    unsigned short* __restrict__ rightT) {
  __shared__ unsigned short WBg[128*128];   // 32KB: value (staging), then gate
  __shared__ unsigned short xs[64*128];     // 16KB x tile (chunk-swizzled)
  const int t = threadIdx.x, wave = t >> 6, lane = t & 63;
  const int fr = lane & 15, kg = lane >> 4;
  const int rg = wave >> 2;        // 0..1: rows rg*32 + [0,32)
  const int cg = wave & 3;         // 0..3: cols cg*32 + [0,32)

  const int side = blockIdx.x >> 9;
  const unsigned short* W = wtall + (size_t)side * 2 * 16384;
  const float* bvp = side ? b_right : b_left;
  const float* bgp = side ? b_rgate : b_lgate;
  unsigned short* dst = side ? rightT : leftT;

  const int tile0 = (blockIdx.x & 511) * 8;

  // stage VALUE weight (2048 chunks / 512 thr = 4 per thread)
  #pragma unroll
  for (int m = 0; m < 4; ++m) {
    int qb = m*512 + wave*64;
    gl_lds16(W + (size_t)(qb + lane)*8, WBg + qb*8);
  }
  // prefetch x tile 0 into regs (linear 32B per thread of swizzled layout)
  uint4 xr0, xr1;
  {
    const uint4* src = (const uint4*)(xbf + (size_t)tile0*64*CDIM);
    xr0 = src[t*2]; xr1 = src[t*2 + 1];
  }
  __syncthreads();   // value weights ready

  // hoist VALUE weight frags to registers: 2 nf x 4 ks (32 VGPRs)
  bf16x8 bv[2][4];
  #pragma unroll
  for (int nf = 0; nf < 2; ++nf) {
    int n = cg*32 + nf*16 + fr;
    #pragma unroll
    for (int ks = 0; ks < 4; ++ks)
      bv[nf][ks] = *(const bf16x8*)(WBg + n*128 + (((ks*4 + kg) ^ (n & 7)) * 8));
  }
  __syncthreads();   // all hoists done before overwriting WBg

  // stage GATE weight into WBg (in flight; drained by first in-loop barrier)
  #pragma unroll
  for (int m = 0; m < 4; ++m) {
    int qb = m*512 + wave*64;
    gl_lds16(W + 16384 + (size_t)(qb + lane)*8, WBg + qb*8);
  }

  const f32x4 fz = {0.f,0.f,0.f,0.f};
  const int n0 = cg*32 + fr, n1 = cg*32 + 16 + fr;
  for (int tt = 0; tt < 8; ++tt) {
    const int p0 = (tile0 + tt) * 64;
    // x tile -> LDS (linear relay preserves swizzle)
    *(uint4*)(xs + t*16)     = xr0;
    *(uint4*)(xs + t*16 + 8) = xr1;
    __syncthreads();   // xs ready (tt==0: gate DMA drained too)

    if (tt < 7) {      // issue next tile's loads; land during MFMA phase
      const uint4* src = (const uint4*)(xbf + (size_t)(p0 + 64)*CDIM);
      xr0 = src[t*2]; xr1 = src[t*2 + 1];
    }

    // per-ks: A frags (2 rf) + gate frags from LDS + value frags from regs
    f32x4 accV[2][2], accG[2][2];   // [rf][nf]
    #pragma unroll
    for (int rf = 0; rf < 2; ++rf)
      #pragma unroll
      for (int nf = 0; nf < 2; ++nf) { accV[rf][nf] = fz; accG[rf][nf] = fz; }

    #pragma unroll
    for (int ks = 0; ks < 4; ++ks) {
      int ar0 = rg*32 + fr, ar1 = rg*32 + 16 + fr;
      bf16x8 a0 = *(const bf16x8*)(xs + ar0*128 + (((ks*4 + kg) ^ (ar0 & 7)) * 8));
      bf16x8 a1 = *(const bf16x8*)(xs + ar1*128 + (((ks*4 + kg) ^ (ar1 & 7)) * 8));
      bf16x8 g0 = *(const bf16x8*)(WBg + n0*128 + (((ks*4 + kg) ^ (n0 & 7)) * 8));
      bf16x8 g1 = *(const bf16x8*)(WBg + n1*128 + (((ks*4 + kg) ^ (n1 & 7)) * 8));
      accG[0][0] = __builtin_amdgcn_mfma_f32_16x16x32_bf16(a0, g0, accG[0][0], 0,0,0);
      accG[0][1] = __builtin_amdgcn_mfma_f32_16x16x32_bf16(a0, g1, accG[0][1], 0,0,0);
      accG[1][0] = __builtin_amdgcn_mfma_f32_16x16x32_bf16(a1, g0, accG[1][0], 0,0,0);
      accG[1][1] = __builtin_amdgcn_mfma_f32_16x16x32_bf16(a1, g1, accG[1][1], 0,0,0);
      accV[0][0] = __builtin_amdgcn_mfma_f32_16x16x32_bf16(a0, bv[0][ks], accV[0][0], 0,0,0);
      accV[0][1] = __builtin_amdgcn_mfma_f32_16x16x32_bf16(a0, bv[1][ks], accV[0][1], 0,0,0);
      accV[1][0] = __builtin_amdgcn_mfma_f32_16x16x32_bf16(a1, bv[0][ks], accV[1][0], 0,0,0);
      accV[1][1] = __builtin_amdgcn_mfma_f32_16x16x32_bf16(a1, bv[1][ks], accV[1][1], 0,0,0);
    }

    // epilogue: gate + mask; pack 4 consecutive positions -> 8B stores
    float mi = mask[p0 >> 9];
    #pragma unroll
    for (int rf = 0; rf < 2; ++rf) {
      const int rbase = rg*32 + rf*16 + kg*4;
      float pm[4];
      #pragma unroll
      for (int jj = 0; jj < 4; ++jj)
        pm[jj] = mi * mask[(p0 & 511) + rbase + jj];
      #pragma unroll
      for (int nf = 0; nf < 2; ++nf) {
        int n = cg*32 + nf*16 + fr;
        float bvn = bvp[n], bgn = bgp[n];
        union { unsigned short u[4]; uint2 v; } pl;
        #pragma unroll
        for (int jj = 0; jj < 4; ++jj)
          pl.u[jj] = f2bf((accV[rf][nf][jj] + bvn) * pm[jj] * sigm(accG[rf][nf][jj] + bgn));
        *(uint2*)(dst + (size_t)n*NPOS + p0 + rbase) = pl.v;
      }
    }
    if (tt < 7) __syncthreads();   // all waves done reading xs
  }
}

// ---------------------------------------------------------------------------
// KB: einsum, 512-thread blocks (16 waves/CU at 64KB LDS). Per block: one
// c-plane, 128x128 tile, K=512, double-buffered. Wave grid 2x4: each wave
// 64 rows x 32 cols. Output bf16 via LDS bounce.
// ---------------------------------------------------------------------------
__global__ __launch_bounds__(512,4) void k_einsum(
    const unsigned short* __restrict__ leftT,
    const unsigned short* __restrict__ rightT,
    unsigned short* __restrict__ eout) {
  __shared__ unsigned short At[2][128*64];   // 2x16KB (also output bounce)
  __shared__ unsigned short Bt[2][128*64];
  const int t = threadIdx.x, wave = t >> 6, lane = t & 63;
  // XCD-chunked swizzle: 16 tiles of one c-plane stay on one XCD (2048 = 8*256)
  int fl = (blockIdx.x & 7) * 256 + (blockIdx.x >> 3);
  const int c = fl >> 4;
  const int i0 = ((fl >> 2) & 3) * 128, j0 = (fl & 3) * 128;
  const unsigned short* Lp = leftT + (size_t)c * NPOS;
  const unsigned short* Rp = rightT + (size_t)c * NPOS;
  const int wrow = (wave >> 2) * 64, wcol = (wave & 3) * 32;
  const int kg = lane >> 4, fr = lane & 15;

  f32x4 acc[4][2];
  const f32x4 fz = {0.f,0.f,0.f,0.f};
  #pragma unroll
  for (int a = 0; a < 4; ++a) { acc[a][0] = fz; acc[a][1] = fz; }

  #define STAGE(buf, kt) do {                                              \
    _Pragma("unroll")                                                      \
    for (int m = 0; m < 2; ++m) {                                          \
      int qb = m*512 + wave*64;                                            \
      int qq = qb + lane;                                                  \
      int r = qq >> 3;                                                     \
      int kk = (qq & 7) ^ (r & 7);                                         \
      gl_lds16(Lp + ((size_t)(i0 + r) << 9) + (kt)*64 + kk*8, At[buf] + qb*8); \
      gl_lds16(Rp + ((size_t)(j0 + r) << 9) + (kt)*64 + kk*8, Bt[buf] + qb*8); \
    }                                                                      \
  } while (0)

  STAGE(0, 0);
  __syncthreads();
  int cur = 0;
  for (int kt = 0; kt < 8; ++kt) {
    if (kt < 7) STAGE(cur ^ 1, kt + 1);
    #pragma unroll
    for (int ks = 0; ks < 2; ++ks) {
      bf16x8 af[4], bfr[2];
      #pragma unroll
      for (int mf = 0; mf < 4; ++mf) {
        int r = wrow + mf*16 + fr;
        af[mf] = *(const bf16x8*)(At[cur] + r*64 + (((ks*4 + kg) ^ (r & 7)) * 8));
      }
      #pragma unroll
      for (int nf = 0; nf < 2; ++nf) {
        int r = wcol + nf*16 + fr;
        bfr[nf] = *(const bf16x8*)(Bt[cur] + r*64 + (((ks*4 + kg) ^ (r & 7)) * 8));
      }
      #pragma unroll
      for (int mf = 0; mf < 4; ++mf)
        #pragma unroll
        for (int nf = 0; nf < 2; ++nf)
          acc[mf][nf] = __builtin_amdgcn_mfma_f32_16x16x32_bf16(af[mf], bfr[nf], acc[mf][nf], 0,0,0);
    }
    __syncthreads();   // drains vmcnt (next tile staged) + all reads of cur done
    cur ^= 1;
  }
  #undef STAGE

  // epilogue: acc -> bounce (bank-swizzled [ri][ci]) -> full-line bf16 stores
  unsigned short* bounce = &At[0][0];   // 32KB
  const int rb = kg << 2;
  #pragma unroll
  for (int mf = 0; mf < 4; ++mf) {
    #pragma unroll
    for (int nf = 0; nf < 2; ++nf) {
      #pragma unroll
      for (int jj = 0; jj < 4; ++jj) {
        int ri = wrow + mf*16 + rb + jj;
        int ci = wcol + nf*16 + fr;
        bounce[ri*128 + (((ci >> 3) ^ (ri & 7)) << 3) + (ci & 7)] = f2bf(acc[mf][nf][jj]);
      }
    }
  }
  __syncthreads();
  unsigned short* op = eout + (size_t)c * NPOS;
  #pragma unroll
  for (int rr = 0; rr < 4; ++rr) {
    int flat = rr*512 + t;
    int row = flat >> 4, ch = flat & 15;
    uint4 v = *(const uint4*)(bounce + row*128 + ((ch ^ (row & 7)) << 3));
    *(uint4*)(op + (size_t)(i0 + row)*LDIM + j0 + ch*8) = v;
  }
}

// ---------------------------------------------------------------------------
// KC: 512 thr, 8 tiles of 64 positions per block (512 blocks). Both weights
// staged ONCE (64KB). x/eout tiles double-buffered via reg-relay (T14).
// ---------------------------------------------------------------------------
__global__ __launch_bounds__(512,2) void k_stageC(
    const unsigned short* __restrict__ eout,
    const unsigned short* __restrict__ xbf,
    const unsigned short* __restrict__ wtall,
    const float* __restrict__ fns, const float* __restrict__ fnb,
    const float* __restrict__ b_out, const float* __restrict__ b_fg,
    float* __restrict__ outp) {
  __shared__ unsigned short WB[2][128*128];  // 64KB: WB0=w_fgate, WB1=w_out
  __shared__ unsigned short xs[2][64*128];   // 32KB x tiles (chunk-swizzled)
  __shared__ unsigned short es[2][64*128];   // 32KB eout tiles [c][pos] -> ytile [pos][c]
  __shared__ float psum[2][8][64];           // 4KB partial LN sums
  const int t = threadIdx.x, wave = t >> 6, lane = t & 63;
  const int fr = lane & 15, kg = lane >> 4;
  const int rg = wave >> 1, cg = wave & 1;
  const int ar = rg*16 + fr;
  const int rbase = rg*16 + kg*4;

  // stage both weights once (2048 chunks each / 512 thr = 4 per thread per mat)
  #pragma unroll
  for (int m = 0; m < 4; ++m) {
    int qb = m*512 + wave*64;
    gl_lds16(wtall + 5*16384 + (size_t)(qb + lane)*8, WB[0] + qb*8);  // w_fgate
    gl_lds16(wtall + 4*16384 + (size_t)(qb + lane)*8, WB[1] + qb*8);  // w_out
  }

  const int tile0 = blockIdx.x * 8;
  uint4 xr0, xr1, er0, er1;
  {
    const uint4* xsrc = (const uint4*)(xbf + (size_t)tile0*64*CDIM);
    xr0 = xsrc[t]; xr1 = xsrc[512 + t];
    const unsigned short* eb = eout + (size_t)tile0*64;
    er0 = *(const uint4*)(eb + (size_t)(t >> 3)*NPOS + (t & 7)*8);          // c = t>>3
    er1 = *(const uint4*)(eb + (size_t)(64 + (t >> 3))*NPOS + (t & 7)*8);   // c = 64+t>>3
  }
  *(uint4*)(xs[0] + t*8) = xr0; *(uint4*)(xs[0] + 4096 + t*8) = xr1;
  *(uint4*)(es[0] + t*8) = er0; *(uint4*)(es[0] + 4096 + t*8) = er1;

  int cur = 0;
  const f32x4 fz = {0.f,0.f,0.f,0.f};
  for (int tt = 0; tt < 8; ++tt) {
    const int p0 = (tile0 + tt) * 64;
    __syncthreads();   // A: cur tile visible (first iter: weights drained too)

    if (tt < 7) {      // T14 issue-early: next tile's loads fly during compute
      const uint4* xsrc = (const uint4*)(xbf + (size_t)(p0 + 64)*CDIM);
      xr0 = xsrc[t]; xr1 = xsrc[512 + t];
      const unsigned short* eb = eout + (size_t)(p0 + 64);
      er0 = *(const uint4*)(eb + (size_t)(t >> 3)*NPOS + (t & 7)*8);
      er1 = *(const uint4*)(eb + (size_t)(64 + (t >> 3))*NPOS + (t & 7)*8);
    }

    // ---- LN over c: wave owns c=[wave*16,+16), lane = pos (conflict-free)
    float ev[16];
    #pragma unroll
    for (int j = 0; j < 16; ++j)
      ev[j] = bf2f(es[cur][(wave*16 + j)*64 + lane]);
    float s = 0.f, s2 = 0.f;
    #pragma unroll
    for (int j = 0; j < 16; ++j) { s += ev[j]; s2 += ev[j]*ev[j]; }
    psum[0][wave][lane] = s; psum[1][wave][lane] = s2;
    __syncthreads();   // B: partials ready (all es reads done)
    float st = 0.f, s2t = 0.f;
    #pragma unroll
    for (int w = 0; w < 8; ++w) { st += psum[0][w][lane]; s2t += psum[1][w][lane]; }
    float mu = st * 0.0078125f;
    float rs = rsqrtf(fmaxf(s2t * 0.0078125f - mu*mu, 0.f) + 1e-5f);

    // x A-fragments + fgate matmul
    bf16x8 afr[4];
    #pragma unroll
    for (int ks = 0; ks < 4; ++ks)
      afr[ks] = *(const bf16x8*)(xs[cur] + ar*128 + (((ks*4 + kg) ^ (ar & 7)) * 8));

    f32x4 accG[4], accY[4];
    #pragma unroll
    for (int nf = 0; nf < 4; ++nf) {
      accG[nf] = fz;
      int n = cg*64 + nf*16 + fr;
      #pragma unroll
      for (int ks = 0; ks < 4; ++ks) {
        bf16x8 b = *(const bf16x8*)(WB[0] + n*128 + (((ks*4 + kg) ^ (n & 7)) * 8));
        accG[nf] = __builtin_amdgcn_mfma_f32_16x16x32_bf16(afr[ks], b, accG[nf], 0,0,0);
      }
    }

    // normalized ytile -> es[cur] as [pos=lane][c] chunk-swizzled
    #pragma unroll
    for (int k = 0; k < 2; ++k) {
      union { unsigned short u[8]; uint4 v; } pk;
      #pragma unroll
      for (int e4 = 0; e4 < 2; ++e4) {
        float4 fsv = ((const float4*)fns)[wave*4 + k*2 + e4];
        float4 fbv = ((const float4*)fnb)[wave*4 + k*2 + e4];
        int j = k*8 + e4*4;
        pk.u[e4*4+0] = f2bf((ev[j+0]-mu)*rs*fsv.x + fbv.x);
        pk.u[e4*4+1] = f2bf((ev[j+1]-mu)*rs*fsv.y + fbv.y);
        pk.u[e4*4+2] = f2bf((ev[j+2]-mu)*rs*fsv.z + fbv.z);
        pk.u[e4*4+3] = f2bf((ev[j+3]-mu)*rs*fsv.w + fbv.w);
      }
      int ch = wave*2 + k;
      int slot = ch ^ (lane & 7);
      *(uint4*)(es[cur] + lane*128 + slot*8) = pk.v;
    }
    __syncthreads();   // C: ytile visible

    bf16x8 yfr[4];
    #pragma unroll
    for (int ks = 0; ks < 4; ++ks)
      yfr[ks] = *(const bf16x8*)(es[cur] + ar*128 + (((ks*4 + kg) ^ (ar & 7)) * 8));
    #pragma unroll
    for (int nf = 0; nf < 4; ++nf) {
      accY[nf] = fz;
      int n = cg*64 + nf*16 + fr;
      #pragma unroll
      for (int ks = 0; ks < 4; ++ks) {
        bf16x8 b = *(const bf16x8*)(WB[1] + n*128 + (((ks*4 + kg) ^ (n & 7)) * 8));
        accY[nf] = __builtin_amdgcn_mfma_f32_16x16x32_bf16(yfr[ks], b, accY[nf], 0,0,0);
      }
    }

    // epilogue: gate + store f32 (16 lanes x 4B = full 64B lines)
    #pragma unroll
    for (int nf = 0; nf < 4; ++nf) {
      int n = cg*64 + nf*16 + fr;
      float bo = b_out[n], bfg = b_fg[n];
      #pragma unroll
      for (int jj = 0; jj < 4; ++jj) {
        float val = (accY[nf][jj] + bo) * sigm(accG[nf][jj] + bfg);
        outp[(size_t)(p0 + rbase + jj)*CDIM + n] = val;
      }
    }

    if (tt < 7) {   // T14 write-late into alternate buffer
      *(uint4*)(xs[cur^1] + t*8) = xr0; *(uint4*)(xs[cur^1] + 4096 + t*8) = xr1;
      *(uint4*)(es[cur^1] + t*8) = er0; *(uint4*)(es[cur^1] + 4096 + t*8) = er1;
      cur ^= 1;
    }
  }
}

// ---------------------------------------------------------------------------
extern "C" void kernel_launch(void* const* d_in, const int* in_sizes, int n_in,
                              void* d_out, int out_size, void* d_ws, size_t ws_size,
                              hipStream_t stream) {
  const float* act  = (const float*)d_in[0];
  const float* mask = (const float*)d_in[1];
  const float* nsc  = (const float*)d_in[2];
  const float* nbi  = (const float*)d_in[3];
  const float* w_l  = (const float*)d_in[4];
  const float* b_l  = (const float*)d_in[5];
  const float* w_r  = (const float*)d_in[6];
  const float* b_r  = (const float*)d_in[7];
  const float* w_lg = (const float*)d_in[8];
  const float* b_lg = (const float*)d_in[9];
  const float* w_rg = (const float*)d_in[10];
  const float* b_rg = (const float*)d_in[11];
  const float* fns  = (const float*)d_in[12];
  const float* fnb  = (const float*)d_in[13];
  const float* w_o  = (const float*)d_in[14];
  const float* b_o  = (const float*)d_in[15];
  const float* w_fg = (const float*)d_in[16];
  const float* b_fg = (const float*)d_in[17];
  float* outp = (float*)d_out;

  char* ws = (char*)d_ws;
  unsigned short* xbf    = (unsigned short*)ws;                         // 64MB bf16 x (chunk-swizzled)
  unsigned short* leftT  = (unsigned short*)(ws + ((size_t)64 << 20));  // 64MB [c][i*512+k]
  unsigned short* rightT = (unsigned short*)(ws + ((size_t)128 << 20)); // 64MB
  unsigned short* eout   = (unsigned short*)(ws + ((size_t)192 << 20)); // 64MB bf16 [c][i*512+j]
  unsigned short* wtall  = (unsigned short*)(ws + ((size_t)320 << 20)); // 192KB

  k_prep<<<6, 256, 0, stream>>>(w_l, w_lg, w_r, w_rg, w_o, w_fg, wtall);
  k_ln<<<NPOS/64, 256, 0, stream>>>(act, nsc, nbi, xbf);
  k_proj<<<1024, 512, 0, stream>>>(xbf, mask, b_l, b_lg, b_r, b_rg, wtall, leftT, rightT);
  k_einsum<<<2048, 512, 0, stream>>>(leftT, rightT, eout);
  k_stageC<<<512, 512, 0, stream>>>(eout, xbf, wtall, fns, fnb, b_o, b_fg, outp);
}

// Round 14
// 244.224 us; speedup vs baseline: 1.4887x; 1.4887x over previous
//
#include <hip/hip_runtime.h>
#include <hip/hip_bf16.h>
#include <stdint.h>

#define LDIM 512
#define CDIM 128
#define NPOS (LDIM*LDIM)   // 262144 positions

typedef __attribute__((ext_vector_type(8))) short bf16x8;
typedef __attribute__((ext_vector_type(4))) float f32x4;

__device__ __forceinline__ unsigned short f2bf(float f) {
  union { __hip_bfloat16 h; unsigned short u; } cv;
  cv.h = __float2bfloat16(f);
  return cv.u;
}

__device__ __forceinline__ float bf2f(unsigned short u) {
  union { unsigned int i; float f; } cv; cv.i = ((unsigned int)u) << 16; return cv.f;
}

__device__ __forceinline__ float sigm(float x) { return 1.0f / (1.0f + __expf(-x)); }

// async global->LDS, 16B per lane. LDS dest must be wave-uniform; HW adds lane*16.
__device__ __forceinline__ void gl_lds16(const unsigned short* g, unsigned short* l) {
  __builtin_amdgcn_global_load_lds(
      (const __attribute__((address_space(1))) unsigned int*)g,
      (__attribute__((address_space(3))) unsigned int*)l, 16, 0, 0);
}

// ---------------------------------------------------------------------------
// K0: transpose + convert 6 weight matrices (128x128 f32 [k][n]) into
// bf16 Wt[n][k], pre-swizzled: 16B chunk s stored at slot (s ^ (n&7)).
// Slots: 0=w_left 1=w_lgate 2=w_right 3=w_rgate 4=w_out 5=w_fgate
// ---------------------------------------------------------------------------
__global__ __launch_bounds__(256) void k_prep(
    const float* w0, const float* w1, const float* w2,
    const float* w3, const float* w4, const float* w5,
    unsigned short* wtall) {
  __shared__ float tmp[CDIM*CDIM];   // 64KB
  const float* w = (blockIdx.x==0)?w0:(blockIdx.x==1)?w1:(blockIdx.x==2)?w2:
                   (blockIdx.x==3)?w3:(blockIdx.x==4)?w4:w5;
  int t = threadIdx.x;
  #pragma unroll
  for (int m = 0; m < 16; ++m)
    ((float4*)tmp)[m*256 + t] = ((const float4*)w)[m*256 + t];
  __syncthreads();
  unsigned short* out = wtall + (size_t)blockIdx.x * (CDIM*CDIM);
  #pragma unroll
  for (int m = 0; m < 8; ++m) {
    int oc = m*256 + t;            // output 16B chunk index (n*16 + sc)
    int n = oc >> 4, sc = oc & 15;
    int s = sc ^ (n & 7);          // data chunk that lands in slot sc
    union { unsigned short u[8]; uint4 v; } pk;
    #pragma unroll
    for (int e = 0; e < 8; ++e) pk.u[e] = f2bf(tmp[(s*8 + e)*CDIM + n]);
    *(uint4*)(out + (size_t)oc*8) = pk.v;
  }
}

// ---------------------------------------------------------------------------
// K_LN: pure streaming LayerNorm. act (f32 [pos][128]) -> xbf (bf16, chunk-
// swizzled: data chunk ch of row pos stored at slot ch^(pos&7)).
// Lane qq owns chunks {qq, 4+qq, 8+qq, 12+qq} -> full-line stores.
// ---------------------------------------------------------------------------
__global__ __launch_bounds__(256,8) void k_ln(
    const float* __restrict__ act,
    const float* __restrict__ nscale, const float* __restrict__ nbias,
    unsigned short* __restrict__ xbf) {
  const int t = threadIdx.x;
  const int pos = blockIdx.x * 64 + (t >> 2), qq = t & 3;
  const int s = pos & 7;

  float4 av[8];
  const float4* ap = (const float4*)(act + (size_t)pos*CDIM);
  #pragma unroll
  for (int cc = 0; cc < 4; ++cc) {
    int ch = cc*4 + qq;
    av[cc*2]     = ap[ch*2];
    av[cc*2 + 1] = ap[ch*2 + 1];
  }

  float sm = 0.f, s2 = 0.f;
  #pragma unroll
  for (int j = 0; j < 8; ++j) {
    float4 v = av[j];
    sm += v.x + v.y + v.z + v.w;
    s2 += v.x*v.x + v.y*v.y + v.z*v.z + v.w*v.w;
  }
  sm += __shfl_xor(sm, 1); s2 += __shfl_xor(s2, 1);
  sm += __shfl_xor(sm, 2); s2 += __shfl_xor(s2, 2);
  float mu = sm * 0.0078125f;
  float rs = rsqrtf(fmaxf(s2 * 0.0078125f - mu*mu, 0.f) + 1e-5f);

  unsigned short* xp = xbf + (size_t)pos * CDIM;
  #pragma unroll
  for (int cc = 0; cc < 4; ++cc) {
    int ch = cc*4 + qq;
    union { unsigned short u[8]; uint4 v; } pk;
    #pragma unroll
    for (int e2 = 0; e2 < 2; ++e2) {
      float4 v = av[cc*2 + e2];
      float4 fs = ((const float4*)nscale)[ch*2 + e2];
      float4 fb = ((const float4*)nbias)[ch*2 + e2];
      int b = e2*4;
      pk.u[b+0] = f2bf((v.x - mu)*rs*fs.x + fb.x);
      pk.u[b+1] = f2bf((v.y - mu)*rs*fs.y + fb.y);
      pk.u[b+2] = f2bf((v.z - mu)*rs*fs.z + fb.z);
      pk.u[b+3] = f2bf((v.w - mu)*rs*fs.w + fb.w);
    }
    int slot = ch ^ s;
    *(uint4*)(xp + slot*8) = pk.v;
  }
}

// ---------------------------------------------------------------------------
// K_PROJ: x @ {w_value, w_gate} with gating+mask, one SIDE per block:
// blocks [0,512) -> left (w_left,w_lgate), blocks [512,1024) -> right.
// 512 thr (8 waves), 2 weight matrices staged ONCE (64KB) -> 80KB LDS ->
// 2 blocks/CU. Loop over 8 tiles of 64 positions; x-tile relayed
// global->reg->LDS (linear copy of swizzled xbf). 2 barriers per tile.
// ---------------------------------------------------------------------------
__global__ __launch_bounds__(512,4) void k_proj(
    const unsigned short* __restrict__ xbf,
    const float* __restrict__ mask,
    const float* __restrict__ b_left, const float* __restrict__ b_lgate,
    const float* __restrict__ b_right, const float* __restrict__ b_rgate,
    const unsigned short* __restrict__ wtall,
    unsigned short* __restrict__ leftT,
    unsigned short* __restrict__ rightT) {
  __shared__ unsigned short WB[2*128*128];   // 64KB: value, gate
  __shared__ unsigned short xs[64*128];      // 16KB x tile (chunk-swizzled)
  const int t = threadIdx.x, wave = t >> 6, lane = t & 63;
  const int fr = lane & 15, kg = lane >> 4;
  const int rg = wave >> 1, cg = wave & 1;
  const int ar = rg*16 + fr;
  const int rbase = rg*16 + kg*4;

  const int side = blockIdx.x >> 9;
  const unsigned short* W = wtall + (size_t)side * 2 * 16384;
  const float* bv = side ? b_right : b_left;
  const float* bg = side ? b_rgate : b_lgate;
  unsigned short* dst = side ? rightT : leftT;

  // stage both weights once (4096 chunks / 512 thr = 8 per thread)
  #pragma unroll
  for (int m = 0; m < 8; ++m) {
    int qb = m*512 + wave*64;
    gl_lds16(W + (size_t)(qb + lane)*8, WB + qb*8);
  }

  const int tile0 = (blockIdx.x & 511) * 8;
  // prefetch x tile 0 into regs (linear 32B per thread of swizzled layout)
  uint4 xr0, xr1;
  {
    const uint4* src = (const uint4*)(xbf + (size_t)tile0*64*CDIM);
    xr0 = src[t*2]; xr1 = src[t*2 + 1];
  }

  for (int tt = 0; tt < 8; ++tt) {
    const int p0 = (tile0 + tt) * 64;
    // x tile -> LDS (linear relay preserves swizzle)
    *(uint4*)(xs + t*16)     = xr0;
    *(uint4*)(xs + t*16 + 8) = xr1;
    __syncthreads();   // xs ready; (first iter: weights drained too)

    if (tt < 7) {      // issue next tile's loads; land during MFMA phase
      const uint4* src = (const uint4*)(xbf + (size_t)(p0 + 64)*CDIM);
      xr0 = src[t*2]; xr1 = src[t*2 + 1];
    }

    // A fragments
    bf16x8 afr[4];
    #pragma unroll
    for (int ks = 0; ks < 4; ++ks)
      afr[ks] = *(const bf16x8*)(xs + ar*128 + (((ks*4 + kg) ^ (ar & 7)) * 8));

    // 32 MFMAs: 2 weights x 4 col-frags x 4 k-steps
    f32x4 acc[2][4];
    const f32x4 fz = {0.f,0.f,0.f,0.f};
    #pragma unroll
    for (int wi = 0; wi < 2; ++wi) {
      #pragma unroll
      for (int nf = 0; nf < 4; ++nf) {
        acc[wi][nf] = fz;
        int n = cg*64 + nf*16 + fr;
        const unsigned short* Wp = WB + wi*16384 + n*128;
        #pragma unroll
        for (int ks = 0; ks < 4; ++ks) {
          bf16x8 b = *(const bf16x8*)(Wp + (((ks*4 + kg) ^ (n & 7)) * 8));
          acc[wi][nf] = __builtin_amdgcn_mfma_f32_16x16x32_bf16(afr[ks], b, acc[wi][nf], 0,0,0);
        }
      }
    }

    // epilogue: gate + mask; pack 4 consecutive positions -> 8B stores
    float mi = mask[p0 >> 9];
    float pm[4];
    #pragma unroll
    for (int jj = 0; jj < 4; ++jj)
      pm[jj] = mi * mask[(p0 & 511) + rbase + jj];
    #pragma unroll
    for (int nf = 0; nf < 4; ++nf) {
      int n = cg*64 + nf*16 + fr;
      float bvn = bv[n], bgn = bg[n];
      union { unsigned short u[4]; uint2 v; } pl;
      #pragma unroll
      for (int jj = 0; jj < 4; ++jj)
        pl.u[jj] = f2bf((acc[0][nf][jj] + bvn) * pm[jj] * sigm(acc[1][nf][jj] + bgn));
      *(uint2*)(dst + (size_t)n*NPOS + p0 + rbase) = pl.v;
    }
    if (tt < 7) __syncthreads();   // all waves done reading xs
  }
}

// ---------------------------------------------------------------------------
// KB: einsum. Per block: one c-plane, 128x128 output tile, K=512, double-buffered.
// out[c][i][j] = sum_k L[c][i][k] * R[c][j][k]. Output bf16 via LDS bounce.
// ---------------------------------------------------------------------------
__global__ __launch_bounds__(256,2) void k_einsum(
    const unsigned short* __restrict__ leftT,
    const unsigned short* __restrict__ rightT,
    unsigned short* __restrict__ eout) {
  __shared__ unsigned short At[2][128*64];   // 2x16KB (also output bounce)
  __shared__ unsigned short Bt[2][128*64];
  const int t = threadIdx.x, wave = t >> 6, lane = t & 63;
  // XCD-chunked swizzle: 16 tiles of one c-plane stay on one XCD (2048 = 8*256)
  int fl = (blockIdx.x & 7) * 256 + (blockIdx.x >> 3);
  const int c = fl >> 4;
  const int i0 = ((fl >> 2) & 3) * 128, j0 = (fl & 3) * 128;
  const unsigned short* Lp = leftT + (size_t)c * NPOS;
  const unsigned short* Rp = rightT + (size_t)c * NPOS;
  const int wrow = (wave >> 1) * 64, wcol = (wave & 1) * 64;
  const int kg = lane >> 4, fr = lane & 15;

  f32x4 acc[4][4];
  const f32x4 fz = {0.f,0.f,0.f,0.f};
  #pragma unroll
  for (int a = 0; a < 4; ++a)
    #pragma unroll
    for (int b = 0; b < 4; ++b) acc[a][b] = fz;

  #define STAGE(buf, kt) do {                                              \
    _Pragma("unroll")                                                      \
    for (int m = 0; m < 4; ++m) {                                          \
      int qb = m*256 + wave*64;                                            \
      int qq = qb + lane;                                                  \
      int r = qq >> 3;                                                     \
      int kk = (qq & 7) ^ (r & 7);                                         \
      gl_lds16(Lp + ((size_t)(i0 + r) << 9) + (kt)*64 + kk*8, At[buf] + qb*8); \
      gl_lds16(Rp + ((size_t)(j0 + r) << 9) + (kt)*64 + kk*8, Bt[buf] + qb*8); \
    }                                                                      \
  } while (0)

  STAGE(0, 0);
  __syncthreads();
  int cur = 0;
  for (int kt = 0; kt < 8; ++kt) {
    if (kt < 7) STAGE(cur ^ 1, kt + 1);
    #pragma unroll
    for (int ks = 0; ks < 2; ++ks) {
      bf16x8 af[4], bfr[4];
      #pragma unroll
      for (int mf = 0; mf < 4; ++mf) {
        int r = wrow + mf*16 + fr;
        af[mf] = *(const bf16x8*)(At[cur] + r*64 + (((ks*4 + kg) ^ (r & 7)) * 8));
      }
      #pragma unroll
      for (int nf = 0; nf < 4; ++nf) {
        int r = wcol + nf*16 + fr;
        bfr[nf] = *(const bf16x8*)(Bt[cur] + r*64 + (((ks*4 + kg) ^ (r & 7)) * 8));
      }
      #pragma unroll
      for (int mf = 0; mf < 4; ++mf)
        #pragma unroll
        for (int nf = 0; nf < 4; ++nf)
          acc[mf][nf] = __builtin_amdgcn_mfma_f32_16x16x32_bf16(af[mf], bfr[nf], acc[mf][nf], 0,0,0);
    }
    __syncthreads();   // drains vmcnt (next tile staged) + all reads of cur done
    cur ^= 1;
  }
  #undef STAGE

  // epilogue: acc -> bounce (bank-swizzled [ri][ci]) -> full-line bf16 stores
  unsigned short* bounce = &At[0][0];   // 32KB
  const int rb = kg << 2;
  #pragma unroll
  for (int mf = 0; mf < 4; ++mf) {
    #pragma unroll
    for (int nf = 0; nf < 4; ++nf) {
      #pragma unroll
      for (int jj = 0; jj < 4; ++jj) {
        int ri = wrow + mf*16 + rb + jj;
        int ci = wcol + nf*16 + fr;
        bounce[ri*128 + (((ci >> 3) ^ (ri & 7)) << 3) + (ci & 7)] = f2bf(acc[mf][nf][jj]);
      }
    }
  }
  __syncthreads();
  unsigned short* op = eout + (size_t)c * NPOS;
  #pragma unroll
  for (int rr = 0; rr < 8; ++rr) {
    int flat = rr*256 + t;
    int row = flat >> 4, ch = flat & 15;
    uint4 v = *(const uint4*)(bounce + row*128 + ((ch ^ (row & 7)) << 3));
    *(uint4*)(op + (size_t)(i0 + row)*LDIM + j0 + ch*8) = v;
  }
}

// ---------------------------------------------------------------------------
// KC: 512 thr, 8 tiles of 64 positions per block (512 blocks). Both weights
// staged ONCE (64KB). x/eout tiles double-buffered via reg-relay (T14:
// issue-early after barrier A, write-late into alternate buffer). 3 barriers
// per tile. LN over c via 8-wave psum; ytile reuses es[cur] (XOR-swizzled,
// bank-conflict-free). LDS 132KB -> 1 block/CU (8 waves).
// ---------------------------------------------------------------------------
__global__ __launch_bounds__(512,2) void k_stageC(
    const unsigned short* __restrict__ eout,
    const unsigned short* __restrict__ xbf,
    const unsigned short* __restrict__ wtall,
    const float* __restrict__ fns, const float* __restrict__ fnb,
    const float* __restrict__ b_out, const float* __restrict__ b_fg,
    float* __restrict__ outp) {
  __shared__ unsigned short WB[2][128*128];  // 64KB: WB0=w_fgate, WB1=w_out
  __shared__ unsigned short xs[2][64*128];   // 32KB x tiles (chunk-swizzled)
  __shared__ unsigned short es[2][64*128];   // 32KB eout tiles [c][pos] -> ytile [pos][c]
  __shared__ float psum[2][8][64];           // 4KB partial LN sums
  const int t = threadIdx.x, wave = t >> 6, lane = t & 63;
  const int fr = lane & 15, kg = lane >> 4;
  const int rg = wave >> 1, cg = wave & 1;
  const int ar = rg*16 + fr;
  const int rbase = rg*16 + kg*4;

  // stage both weights once (2048 chunks each / 512 thr = 4 per thread per mat)
  #pragma unroll
  for (int m = 0; m < 4; ++m) {
    int qb = m*512 + wave*64;
    gl_lds16(wtall + 5*16384 + (size_t)(qb + lane)*8, WB[0] + qb*8);  // w_fgate
    gl_lds16(wtall + 4*16384 + (size_t)(qb + lane)*8, WB[1] + qb*8);  // w_out
  }

  const int tile0 = blockIdx.x * 8;
  uint4 xr0, xr1, er0, er1;
  {
    const uint4* xsrc = (const uint4*)(xbf + (size_t)tile0*64*CDIM);
    xr0 = xsrc[t]; xr1 = xsrc[512 + t];
    const unsigned short* eb = eout + (size_t)tile0*64;
    er0 = *(const uint4*)(eb + (size_t)(t >> 3)*NPOS + (t & 7)*8);          // c = t>>3
    er1 = *(const uint4*)(eb + (size_t)(64 + (t >> 3))*NPOS + (t & 7)*8);   // c = 64+t>>3
  }
  *(uint4*)(xs[0] + t*8) = xr0; *(uint4*)(xs[0] + 4096 + t*8) = xr1;
  *(uint4*)(es[0] + t*8) = er0; *(uint4*)(es[0] + 4096 + t*8) = er1;

  int cur = 0;
  const f32x4 fz = {0.f,0.f,0.f,0.f};
  for (int tt = 0; tt < 8; ++tt) {
    const int p0 = (tile0 + tt) * 64;
    __syncthreads();   // A: cur tile visible (first iter: weights drained too)

    if (tt < 7) {      // T14 issue-early: next tile's loads fly during compute
      const uint4* xsrc = (const uint4*)(xbf + (size_t)(p0 + 64)*CDIM);
      xr0 = xsrc[t]; xr1 = xsrc[512 + t];
      const unsigned short* eb = eout + (size_t)(p0 + 64);
      er0 = *(const uint4*)(eb + (size_t)(t >> 3)*NPOS + (t & 7)*8);
      er1 = *(const uint4*)(eb + (size_t)(64 + (t >> 3))*NPOS + (t & 7)*8);
    }

    // ---- LN over c: wave owns c=[wave*16,+16), lane = pos (conflict-free)
    float ev[16];
    #pragma unroll
    for (int j = 0; j < 16; ++j)
      ev[j] = bf2f(es[cur][(wave*16 + j)*64 + lane]);
    float s = 0.f, s2 = 0.f;
    #pragma unroll
    for (int j = 0; j < 16; ++j) { s += ev[j]; s2 += ev[j]*ev[j]; }
    psum[0][wave][lane] = s; psum[1][wave][lane] = s2;
    __syncthreads();   // B: partials ready (all es reads done)
    float st = 0.f, s2t = 0.f;
    #pragma unroll
    for (int w = 0; w < 8; ++w) { st += psum[0][w][lane]; s2t += psum[1][w][lane]; }
    float mu = st * 0.0078125f;
    float rs = rsqrtf(fmaxf(s2t * 0.0078125f - mu*mu, 0.f) + 1e-5f);

    // x A-fragments + fgate matmul
    bf16x8 afr[4];
    #pragma unroll
    for (int ks = 0; ks < 4; ++ks)
      afr[ks] = *(const bf16x8*)(xs[cur] + ar*128 + (((ks*4 + kg) ^ (ar & 7)) * 8));

    f32x4 accG[4], accY[4];
    #pragma unroll
    for (int nf = 0; nf < 4; ++nf) {
      accG[nf] = fz;
      int n = cg*64 + nf*16 + fr;
      #pragma unroll
      for (int ks = 0; ks < 4; ++ks) {
        bf16x8 b = *(const bf16x8*)(WB[0] + n*128 + (((ks*4 + kg) ^ (n & 7)) * 8));
        accG[nf] = __builtin_amdgcn_mfma_f32_16x16x32_bf16(afr[ks], b, accG[nf], 0,0,0);
      }
    }

    // normalized ytile -> es[cur] as [pos=lane][c] chunk-swizzled
    #pragma unroll
    for (int k = 0; k < 2; ++k) {
      union { unsigned short u[8]; uint4 v; } pk;
      #pragma unroll
      for (int e4 = 0; e4 < 2; ++e4) {
        float4 fsv = ((const float4*)fns)[wave*4 + k*2 + e4];
        float4 fbv = ((const float4*)fnb)[wave*4 + k*2 + e4];
        int j = k*8 + e4*4;
        pk.u[e4*4+0] = f2bf((ev[j+0]-mu)*rs*fsv.x + fbv.x);
        pk.u[e4*4+1] = f2bf((ev[j+1]-mu)*rs*fsv.y + fbv.y);
        pk.u[e4*4+2] = f2bf((ev[j+2]-mu)*rs*fsv.z + fbv.z);
        pk.u[e4*4+3] = f2bf((ev[j+3]-mu)*rs*fsv.w + fbv.w);
      }
      int ch = wave*2 + k;
      int slot = ch ^ (lane & 7);
      *(uint4*)(es[cur] + lane*128 + slot*8) = pk.v;
    }
    __syncthreads();   // C: ytile visible

    bf16x8 yfr[4];
    #pragma unroll
    for (int ks = 0; ks < 4; ++ks)
      yfr[ks] = *(const bf16x8*)(es[cur] + ar*128 + (((ks*4 + kg) ^ (ar & 7)) * 8));
    #pragma unroll
    for (int nf = 0; nf < 4; ++nf) {
      accY[nf] = fz;
      int n = cg*64 + nf*16 + fr;
      #pragma unroll
      for (int ks = 0; ks < 4; ++ks) {
        bf16x8 b = *(const bf16x8*)(WB[1] + n*128 + (((ks*4 + kg) ^ (n & 7)) * 8));
        accY[nf] = __builtin_amdgcn_mfma_f32_16x16x32_bf16(yfr[ks], b, accY[nf], 0,0,0);
      }
    }

    // epilogue: gate + store f32 (16 lanes x 4B = full 64B lines)
    #pragma unroll
    for (int nf = 0; nf < 4; ++nf) {
      int n = cg*64 + nf*16 + fr;
      float bo = b_out[n], bfg = b_fg[n];
      #pragma unroll
      for (int jj = 0; jj < 4; ++jj) {
        float val = (accY[nf][jj] + bo) * sigm(accG[nf][jj] + bfg);
        outp[(size_t)(p0 + rbase + jj)*CDIM + n] = val;
      }
    }

    if (tt < 7) {   // T14 write-late into alternate buffer
      *(uint4*)(xs[cur^1] + t*8) = xr0; *(uint4*)(xs[cur^1] + 4096 + t*8) = xr1;
      *(uint4*)(es[cur^1] + t*8) = er0; *(uint4*)(es[cur^1] + 4096 + t*8) = er1;
      cur ^= 1;
    }
  }
}

// ---------------------------------------------------------------------------
extern "C" void kernel_launch(void* const* d_in, const int* in_sizes, int n_in,
                              void* d_out, int out_size, void* d_ws, size_t ws_size,
                              hipStream_t stream) {
  const float* act  = (const float*)d_in[0];
  const float* mask = (const float*)d_in[1];
  const float* nsc  = (const float*)d_in[2];
  const float* nbi  = (const float*)d_in[3];
  const float* w_l  = (const float*)d_in[4];
  const float* b_l  = (const float*)d_in[5];
  const float* w_r  = (const float*)d_in[6];
  const float* b_r  = (const float*)d_in[7];
  const float* w_lg = (const float*)d_in[8];
  const float* b_lg = (const float*)d_in[9];
  const float* w_rg = (const float*)d_in[10];
  const float* b_rg = (const float*)d_in[11];
  const float* fns  = (const float*)d_in[12];
  const float* fnb  = (const float*)d_in[13];
  const float* w_o  = (const float*)d_in[14];
  const float* b_o  = (const float*)d_in[15];
  const float* w_fg = (const float*)d_in[16];
  const float* b_fg = (const float*)d_in[17];
  float* outp = (float*)d_out;

  char* ws = (char*)d_ws;
  unsigned short* xbf    = (unsigned short*)ws;                         // 64MB bf16 x (chunk-swizzled)
  unsigned short* leftT  = (unsigned short*)(ws + ((size_t)64 << 20));  // 64MB [c][i*512+k]
  unsigned short* rightT = (unsigned short*)(ws + ((size_t)128 << 20)); // 64MB
  unsigned short* eout   = (unsigned short*)(ws + ((size_t)192 << 20)); // 64MB bf16 [c][i*512+j]
  unsigned short* wtall  = (unsigned short*)(ws + ((size_t)320 << 20)); // 192KB

  k_prep<<<6, 256, 0, stream>>>(w_l, w_lg, w_r, w_rg, w_o, w_fg, wtall);
  k_ln<<<NPOS/64, 256, 0, stream>>>(act, nsc, nbi, xbf);
  k_proj<<<1024, 512, 0, stream>>>(xbf, mask, b_l, b_lg, b_r, b_rg, wtall, leftT, rightT);
  k_einsum<<<2048, 256, 0, stream>>>(leftT, rightT, eout);
  k_stageC<<<512, 512, 0, stream>>>(eout, xbf, wtall, fns, fnb, b_o, b_fg, outp);
}

// Round 15
// 236.724 us; speedup vs baseline: 1.5359x; 1.0317x over previous
//
#include <hip/hip_runtime.h>
#include <hip/hip_bf16.h>
#include <stdint.h>

#define LDIM 512
#define CDIM 128
#define NPOS (LDIM*LDIM)   // 262144 positions

typedef __attribute__((ext_vector_type(8))) short bf16x8;
typedef __attribute__((ext_vector_type(4))) float f32x4;

__device__ __forceinline__ unsigned short f2bf(float f) {
  union { __hip_bfloat16 h; unsigned short u; } cv;
  cv.h = __float2bfloat16(f);
  return cv.u;
}

__device__ __forceinline__ float bf2f(unsigned short u) {
  union { unsigned int i; float f; } cv; cv.i = ((unsigned int)u) << 16; return cv.f;
}

__device__ __forceinline__ float sigm(float x) { return 1.0f / (1.0f + __expf(-x)); }

// async global->LDS, 16B per lane. LDS dest must be wave-uniform; HW adds lane*16.
__device__ __forceinline__ void gl_lds16(const unsigned short* g, unsigned short* l) {
  __builtin_amdgcn_global_load_lds(
      (const __attribute__((address_space(1))) unsigned int*)g,
      (__attribute__((address_space(3))) unsigned int*)l, 16, 0, 0);
}

// ---------------------------------------------------------------------------
// K_LN (+prep): blocks [0,4096) = streaming LayerNorm; blocks [4096,4102) =
// weight transpose/convert (one 128x128 matrix each).
// LN: act (f32 [pos][128]) -> xbf (bf16, chunk-swizzled: chunk ch of row pos
// at slot ch^(pos&7)). Lane qq owns chunks {qq,4+qq,8+qq,12+qq} -> full-line
// stores. Prep: Wt[n][k] bf16, chunk s at slot s^(n&7).
// Slots: 0=w_left 1=w_lgate 2=w_right 3=w_rgate 4=w_out 5=w_fgate
// ---------------------------------------------------------------------------
__global__ __launch_bounds__(256,8) void k_ln(
    const float* __restrict__ act,
    const float* __restrict__ nscale, const float* __restrict__ nbias,
    const float* w0, const float* w1, const float* w2,
    const float* w3, const float* w4, const float* w5,
    unsigned short* __restrict__ xbf,
    unsigned short* __restrict__ wtall) {
  const int t = threadIdx.x;
  if (blockIdx.x >= NPOS/64) {   // ---- prep path (6 blocks)
    __shared__ float tmp[CDIM*CDIM];   // 64KB
    const int wi = blockIdx.x - NPOS/64;
    const float* w = (wi==0)?w0:(wi==1)?w1:(wi==2)?w2:(wi==3)?w3:(wi==4)?w4:w5;
    #pragma unroll
    for (int m = 0; m < 16; ++m)
      ((float4*)tmp)[m*256 + t] = ((const float4*)w)[m*256 + t];
    __syncthreads();
    unsigned short* out = wtall + (size_t)wi * (CDIM*CDIM);
    #pragma unroll
    for (int m = 0; m < 8; ++m) {
      int oc = m*256 + t;            // output 16B chunk index (n*16 + sc)
      int n = oc >> 4, sc = oc & 15;
      int s = sc ^ (n & 7);          // data chunk that lands in slot sc
      union { unsigned short u[8]; uint4 v; } pk;
      #pragma unroll
      for (int e = 0; e < 8; ++e) pk.u[e] = f2bf(tmp[(s*8 + e)*CDIM + n]);
      *(uint4*)(out + (size_t)oc*8) = pk.v;
    }
    return;
  }

  const int pos = blockIdx.x * 64 + (t >> 2), qq = t & 3;
  const int s = pos & 7;

  float4 av[8];
  const float4* ap = (const float4*)(act + (size_t)pos*CDIM);
  #pragma unroll
  for (int cc = 0; cc < 4; ++cc) {
    int ch = cc*4 + qq;
    av[cc*2]     = ap[ch*2];
    av[cc*2 + 1] = ap[ch*2 + 1];
  }

  float sm = 0.f, s2 = 0.f;
  #pragma unroll
  for (int j = 0; j < 8; ++j) {
    float4 v = av[j];
    sm += v.x + v.y + v.z + v.w;
    s2 += v.x*v.x + v.y*v.y + v.z*v.z + v.w*v.w;
  }
  sm += __shfl_xor(sm, 1); s2 += __shfl_xor(s2, 1);
  sm += __shfl_xor(sm, 2); s2 += __shfl_xor(s2, 2);
  float mu = sm * 0.0078125f;
  float rs = rsqrtf(fmaxf(s2 * 0.0078125f - mu*mu, 0.f) + 1e-5f);

  unsigned short* xp = xbf + (size_t)pos * CDIM;
  #pragma unroll
  for (int cc = 0; cc < 4; ++cc) {
    int ch = cc*4 + qq;
    union { unsigned short u[8]; uint4 v; } pk;
    #pragma unroll
    for (int e2 = 0; e2 < 2; ++e2) {
      float4 v = av[cc*2 + e2];
      float4 fs = ((const float4*)nscale)[ch*2 + e2];
      float4 fb = ((const float4*)nbias)[ch*2 + e2];
      int b = e2*4;
      pk.u[b+0] = f2bf((v.x - mu)*rs*fs.x + fb.x);
      pk.u[b+1] = f2bf((v.y - mu)*rs*fs.y + fb.y);
      pk.u[b+2] = f2bf((v.z - mu)*rs*fs.z + fb.z);
      pk.u[b+3] = f2bf((v.w - mu)*rs*fs.w + fb.w);
    }
    int slot = ch ^ s;
    *(uint4*)(xp + slot*8) = pk.v;
  }
}

// ---------------------------------------------------------------------------
// K_PROJ: x @ {w_value, w_gate} with gating+mask, one SIDE per block:
// blocks [0,512) -> left (w_left,w_lgate), blocks [512,1024) -> right.
// 512 thr (8 waves), 2 weight matrices staged ONCE (64KB) -> 80KB LDS ->
// 2 blocks/CU. Loop over 8 tiles of 64 positions; x-tile relayed
// global->reg->LDS (linear copy of swizzled xbf). 2 barriers per tile.
// Bias (bvn/bgn per nf) and mask-row scalar (mi) hoisted: block-invariant.
// ---------------------------------------------------------------------------
__global__ __launch_bounds__(512,4) void k_proj(
    const unsigned short* __restrict__ xbf,
    const float* __restrict__ mask,
    const float* __restrict__ b_left, const float* __restrict__ b_lgate,
    const float* __restrict__ b_right, const float* __restrict__ b_rgate,
    const unsigned short* __restrict__ wtall,
    unsigned short* __restrict__ leftT,
    unsigned short* __restrict__ rightT) {
  __shared__ unsigned short WB[2*128*128];   // 64KB: value, gate
  __shared__ unsigned short xs[64*128];      // 16KB x tile (chunk-swizzled)
  const int t = threadIdx.x, wave = t >> 6, lane = t & 63;
  const int fr = lane & 15, kg = lane >> 4;
  const int rg = wave >> 1, cg = wave & 1;
  const int ar = rg*16 + fr;
  const int rbase = rg*16 + kg*4;

  const int side = blockIdx.x >> 9;
  const unsigned short* W = wtall + (size_t)side * 2 * 16384;
  const float* bv = side ? b_right : b_left;
  const float* bg = side ? b_rgate : b_lgate;
  unsigned short* dst = side ? rightT : leftT;

  // stage both weights once (4096 chunks / 512 thr = 8 per thread)
  #pragma unroll
  for (int m = 0; m < 8; ++m) {
    int qb = m*512 + wave*64;
    gl_lds16(W + (size_t)(qb + lane)*8, WB + qb*8);
  }

  const int tile0 = (blockIdx.x & 511) * 8;
  // hoisted block-invariants: bias pairs (n is tile-invariant) + mask row scalar
  float bvn[4], bgn[4];
  #pragma unroll
  for (int nf = 0; nf < 4; ++nf) {
    int n = cg*64 + nf*16 + fr;
    bvn[nf] = bv[n]; bgn[nf] = bg[n];
  }
  const float mi = mask[(tile0 * 64) >> 9];

  // prefetch x tile 0 into regs (linear 32B per thread of swizzled layout)
  uint4 xr0, xr1;
  {
    const uint4* src = (const uint4*)(xbf + (size_t)tile0*64*CDIM);
    xr0 = src[t*2]; xr1 = src[t*2 + 1];
  }

  for (int tt = 0; tt < 8; ++tt) {
    const int p0 = (tile0 + tt) * 64;
    // x tile -> LDS (linear relay preserves swizzle)
    *(uint4*)(xs + t*16)     = xr0;
    *(uint4*)(xs + t*16 + 8) = xr1;
    __syncthreads();   // xs ready; (first iter: weights drained too)

    if (tt < 7) {      // issue next tile's loads; land during MFMA phase
      const uint4* src = (const uint4*)(xbf + (size_t)(p0 + 64)*CDIM);
      xr0 = src[t*2]; xr1 = src[t*2 + 1];
    }

    // A fragments
    bf16x8 afr[4];
    #pragma unroll
    for (int ks = 0; ks < 4; ++ks)
      afr[ks] = *(const bf16x8*)(xs + ar*128 + (((ks*4 + kg) ^ (ar & 7)) * 8));

    // 32 MFMAs: 2 weights x 4 col-frags x 4 k-steps
    f32x4 acc[2][4];
    const f32x4 fz = {0.f,0.f,0.f,0.f};
    #pragma unroll
    for (int wi = 0; wi < 2; ++wi) {
      #pragma unroll
      for (int nf = 0; nf < 4; ++nf) {
        acc[wi][nf] = fz;
        int n = cg*64 + nf*16 + fr;
        const unsigned short* Wp = WB + wi*16384 + n*128;
        #pragma unroll
        for (int ks = 0; ks < 4; ++ks) {
          bf16x8 b = *(const bf16x8*)(Wp + (((ks*4 + kg) ^ (n & 7)) * 8));
          acc[wi][nf] = __builtin_amdgcn_mfma_f32_16x16x32_bf16(afr[ks], b, acc[wi][nf], 0,0,0);
        }
      }
    }

    // epilogue: gate + mask; pack 4 consecutive positions -> 8B stores
    float pm[4];
    #pragma unroll
    for (int jj = 0; jj < 4; ++jj)
      pm[jj] = mi * mask[(p0 & 511) + rbase + jj];
    #pragma unroll
    for (int nf = 0; nf < 4; ++nf) {
      int n = cg*64 + nf*16 + fr;
      union { unsigned short u[4]; uint2 v; } pl;
      #pragma unroll
      for (int jj = 0; jj < 4; ++jj)
        pl.u[jj] = f2bf((acc[0][nf][jj] + bvn[nf]) * pm[jj] * sigm(acc[1][nf][jj] + bgn[nf]));
      *(uint2*)(dst + (size_t)n*NPOS + p0 + rbase) = pl.v;
    }
    if (tt < 7) __syncthreads();   // all waves done reading xs
  }
}

// ---------------------------------------------------------------------------
// KB: einsum. Per block: one c-plane, 128x128 output tile, K=512, double-buffered.
// out[c][i][j] = sum_k L[c][i][k] * R[c][j][k]. Output bf16 via LDS bounce.
// ---------------------------------------------------------------------------
__global__ __launch_bounds__(256,2) void k_einsum(
    const unsigned short* __restrict__ leftT,
    const unsigned short* __restrict__ rightT,
    unsigned short* __restrict__ eout) {
  __shared__ unsigned short At[2][128*64];   // 2x16KB (also output bounce)
  __shared__ unsigned short Bt[2][128*64];
  const int t = threadIdx.x, wave = t >> 6, lane = t & 63;
  // XCD-chunked swizzle: 16 tiles of one c-plane stay on one XCD (2048 = 8*256)
  int fl = (blockIdx.x & 7) * 256 + (blockIdx.x >> 3);
  const int c = fl >> 4;
  const int i0 = ((fl >> 2) & 3) * 128, j0 = (fl & 3) * 128;
  const unsigned short* Lp = leftT + (size_t)c * NPOS;
  const unsigned short* Rp = rightT + (size_t)c * NPOS;
  const int wrow = (wave >> 1) * 64, wcol = (wave & 1) * 64;
  const int kg = lane >> 4, fr = lane & 15;

  f32x4 acc[4][4];
  const f32x4 fz = {0.f,0.f,0.f,0.f};
  #pragma unroll
  for (int a = 0; a < 4; ++a)
    #pragma unroll
    for (int b = 0; b < 4; ++b) acc[a][b] = fz;

  #define STAGE(buf, kt) do {                                              \
    _Pragma("unroll")                                                      \
    for (int m = 0; m < 4; ++m) {                                          \
      int qb = m*256 + wave*64;                                            \
      int qq = qb + lane;                                                  \
      int r = qq >> 3;                                                     \
      int kk = (qq & 7) ^ (r & 7);                                         \
      gl_lds16(Lp + ((size_t)(i0 + r) << 9) + (kt)*64 + kk*8, At[buf] + qb*8); \
      gl_lds16(Rp + ((size_t)(j0 + r) << 9) + (kt)*64 + kk*8, Bt[buf] + qb*8); \
    }                                                                      \
  } while (0)

  STAGE(0, 0);
  __syncthreads();
  int cur = 0;
  for (int kt = 0; kt < 8; ++kt) {
    if (kt < 7) STAGE(cur ^ 1, kt + 1);
    #pragma unroll
    for (int ks = 0; ks < 2; ++ks) {
      bf16x8 af[4], bfr[4];
      #pragma unroll
      for (int mf = 0; mf < 4; ++mf) {
        int r = wrow + mf*16 + fr;
        af[mf] = *(const bf16x8*)(At[cur] + r*64 + (((ks*4 + kg) ^ (r & 7)) * 8));
      }
      #pragma unroll
      for (int nf = 0; nf < 4; ++nf) {
        int r = wcol + nf*16 + fr;
        bfr[nf] = *(const bf16x8*)(Bt[cur] + r*64 + (((ks*4 + kg) ^ (r & 7)) * 8));
      }
      #pragma unroll
      for (int mf = 0; mf < 4; ++mf)
        #pragma unroll
        for (int nf = 0; nf < 4; ++nf)
          acc[mf][nf] = __builtin_amdgcn_mfma_f32_16x16x32_bf16(af[mf], bfr[nf], acc[mf][nf], 0,0,0);
    }
    __syncthreads();   // drains vmcnt (next tile staged) + all reads of cur done
    cur ^= 1;
  }
  #undef STAGE

  // epilogue: acc -> bounce (bank-swizzled [ri][ci]) -> full-line bf16 stores
  unsigned short* bounce = &At[0][0];   // 32KB
  const int rb = kg << 2;
  #pragma unroll
  for (int mf = 0; mf < 4; ++mf) {
    #pragma unroll
    for (int nf = 0; nf < 4; ++nf) {
      #pragma unroll
      for (int jj = 0; jj < 4; ++jj) {
        int ri = wrow + mf*16 + rb + jj;
        int ci = wcol + nf*16 + fr;
        bounce[ri*128 + (((ci >> 3) ^ (ri & 7)) << 3) + (ci & 7)] = f2bf(acc[mf][nf][jj]);
      }
    }
  }
  __syncthreads();
  unsigned short* op = eout + (size_t)c * NPOS;
  #pragma unroll
  for (int rr = 0; rr < 8; ++rr) {
    int flat = rr*256 + t;
    int row = flat >> 4, ch = flat & 15;
    uint4 v = *(const uint4*)(bounce + row*128 + ((ch ^ (row & 7)) << 3));
    *(uint4*)(op + (size_t)(i0 + row)*LDIM + j0 + ch*8) = v;
  }
}

// ---------------------------------------------------------------------------
// KC: 512 thr, 8 tiles of 64 positions per block (512 blocks). Both weights
// staged ONCE (64KB). x/eout tiles double-buffered via reg-relay (T14:
// issue-early after barrier A, write-late into alternate buffer). 3 barriers
// per tile. LN over c via 8-wave psum; ytile reuses es[cur] (XOR-swizzled,
// bank-conflict-free). LDS 132KB -> 1 block/CU (8 waves).
// ---------------------------------------------------------------------------
__global__ __launch_bounds__(512,2) void k_stageC(
    const unsigned short* __restrict__ eout,
    const unsigned short* __restrict__ xbf,
    const unsigned short* __restrict__ wtall,
    const float* __restrict__ fns, const float* __restrict__ fnb,
    const float* __restrict__ b_out, const float* __restrict__ b_fg,
    float* __restrict__ outp) {
  __shared__ unsigned short WB[2][128*128];  // 64KB: WB0=w_fgate, WB1=w_out
  __shared__ unsigned short xs[2][64*128];   // 32KB x tiles (chunk-swizzled)
  __shared__ unsigned short es[2][64*128];   // 32KB eout tiles [c][pos] -> ytile [pos][c]
  __shared__ float psum[2][8][64];           // 4KB partial LN sums
  const int t = threadIdx.x, wave = t >> 6, lane = t & 63;
  const int fr = lane & 15, kg = lane >> 4;
  const int rg = wave >> 1, cg = wave & 1;
  const int ar = rg*16 + fr;
  const int rbase = rg*16 + kg*4;

  // stage both weights once (2048 chunks each / 512 thr = 4 per thread per mat)
  #pragma unroll
  for (int m = 0; m < 4; ++m) {
    int qb = m*512 + wave*64;
    gl_lds16(wtall + 5*16384 + (size_t)(qb + lane)*8, WB[0] + qb*8);  // w_fgate
    gl_lds16(wtall + 4*16384 + (size_t)(qb + lane)*8, WB[1] + qb*8);  // w_out
  }

  const int tile0 = blockIdx.x * 8;
  uint4 xr0, xr1, er0, er1;
  {
    const uint4* xsrc = (const uint4*)(xbf + (size_t)tile0*64*CDIM);
    xr0 = xsrc[t]; xr1 = xsrc[512 + t];
    const unsigned short* eb = eout + (size_t)tile0*64;
    er0 = *(const uint4*)(eb + (size_t)(t >> 3)*NPOS + (t & 7)*8);          // c = t>>3
    er1 = *(const uint4*)(eb + (size_t)(64 + (t >> 3))*NPOS + (t & 7)*8);   // c = 64+t>>3
  }
  *(uint4*)(xs[0] + t*8) = xr0; *(uint4*)(xs[0] + 4096 + t*8) = xr1;
  *(uint4*)(es[0] + t*8) = er0; *(uint4*)(es[0] + 4096 + t*8) = er1;

  int cur = 0;
  const f32x4 fz = {0.f,0.f,0.f,0.f};
  for (int tt = 0; tt < 8; ++tt) {
    const int p0 = (tile0 + tt) * 64;
    __syncthreads();   // A: cur tile visible (first iter: weights drained too)

    if (tt < 7) {      // T14 issue-early: next tile's loads fly during compute
      const uint4* xsrc = (const uint4*)(xbf + (size_t)(p0 + 64)*CDIM);
      xr0 = xsrc[t]; xr1 = xsrc[512 + t];
      const unsigned short* eb = eout + (size_t)(p0 + 64);
      er0 = *(const uint4*)(eb + (size_t)(t >> 3)*NPOS + (t & 7)*8);
      er1 = *(const uint4*)(eb + (size_t)(64 + (t >> 3))*NPOS + (t & 7)*8);
    }

    // ---- LN over c: wave owns c=[wave*16,+16), lane = pos (conflict-free)
    float ev[16];
    #pragma unroll
    for (int j = 0; j < 16; ++j)
      ev[j] = bf2f(es[cur][(wave*16 + j)*64 + lane]);
    float s = 0.f, s2 = 0.f;
    #pragma unroll
    for (int j = 0; j < 16; ++j) { s += ev[j]; s2 += ev[j]*ev[j]; }
    psum[0][wave][lane] = s; psum[1][wave][lane] = s2;
    __syncthreads();   // B: partials ready (all es reads done)
    float st = 0.f, s2t = 0.f;
    #pragma unroll
    for (int w = 0; w < 8; ++w) { st += psum[0][w][lane]; s2t += psum[1][w][lane]; }
    float mu = st * 0.0078125f;
    float rs = rsqrtf(fmaxf(s2t * 0.0078125f - mu*mu, 0.f) + 1e-5f);

    // x A-fragments + fgate matmul
    bf16x8 afr[4];
    #pragma unroll
    for (int ks = 0; ks < 4; ++ks)
      afr[ks] = *(const bf16x8*)(xs[cur] + ar*128 + (((ks*4 + kg) ^ (ar & 7)) * 8));

    f32x4 accG[4], accY[4];
    #pragma unroll
    for (int nf = 0; nf < 4; ++nf) {
      accG[nf] = fz;
      int n = cg*64 + nf*16 + fr;
      #pragma unroll
      for (int ks = 0; ks < 4; ++ks) {
        bf16x8 b = *(const bf16x8*)(WB[0] + n*128 + (((ks*4 + kg) ^ (n & 7)) * 8));
        accG[nf] = __builtin_amdgcn_mfma_f32_16x16x32_bf16(afr[ks], b, accG[nf], 0,0,0);
      }
    }

    // normalized ytile -> es[cur] as [pos=lane][c] chunk-swizzled
    #pragma unroll
    for (int k = 0; k < 2; ++k) {
      union { unsigned short u[8]; uint4 v; } pk;
      #pragma unroll
      for (int e4 = 0; e4 < 2; ++e4) {
        float4 fsv = ((const float4*)fns)[wave*4 + k*2 + e4];
        float4 fbv = ((const float4*)fnb)[wave*4 + k*2 + e4];
        int j = k*8 + e4*4;
        pk.u[e4*4+0] = f2bf((ev[j+0]-mu)*rs*fsv.x + fbv.x);
        pk.u[e4*4+1] = f2bf((ev[j+1]-mu)*rs*fsv.y + fbv.y);
        pk.u[e4*4+2] = f2bf((ev[j+2]-mu)*rs*fsv.z + fbv.z);
        pk.u[e4*4+3] = f2bf((ev[j+3]-mu)*rs*fsv.w + fbv.w);
      }
      int ch = wave*2 + k;
      int slot = ch ^ (lane & 7);
      *(uint4*)(es[cur] + lane*128 + slot*8) = pk.v;
    }
    __syncthreads();   // C: ytile visible

    bf16x8 yfr[4];
    #pragma unroll
    for (int ks = 0; ks < 4; ++ks)
      yfr[ks] = *(const bf16x8*)(es[cur] + ar*128 + (((ks*4 + kg) ^ (ar & 7)) * 8));
    #pragma unroll
    for (int nf = 0; nf < 4; ++nf) {
      accY[nf] = fz;
      int n = cg*64 + nf*16 + fr;
      #pragma unroll
      for (int ks = 0; ks < 4; ++ks) {
        bf16x8 b = *(const bf16x8*)(WB[1] + n*128 + (((ks*4 + kg) ^ (n & 7)) * 8));
        accY[nf] = __builtin_amdgcn_mfma_f32_16x16x32_bf16(yfr[ks], b, accY[nf], 0,0,0);
      }
    }

    // epilogue: gate + store f32 (16 lanes x 4B = full 64B lines)
    #pragma unroll
    for (int nf = 0; nf < 4; ++nf) {
      int n = cg*64 + nf*16 + fr;
      float bo = b_out[n], bfg = b_fg[n];
      #pragma unroll
      for (int jj = 0; jj < 4; ++jj) {
        float val = (accY[nf][jj] + bo) * sigm(accG[nf][jj] + bfg);
        outp[(size_t)(p0 + rbase + jj)*CDIM + n] = val;
      }
    }

    if (tt < 7) {   // T14 write-late into alternate buffer
      *(uint4*)(xs[cur^1] + t*8) = xr0; *(uint4*)(xs[cur^1] + 4096 + t*8) = xr1;
      *(uint4*)(es[cur^1] + t*8) = er0; *(uint4*)(es[cur^1] + 4096 + t*8) = er1;
      cur ^= 1;
    }
  }
}

// ---------------------------------------------------------------------------
extern "C" void kernel_launch(void* const* d_in, const int* in_sizes, int n_in,
                              void* d_out, int out_size, void* d_ws, size_t ws_size,
                              hipStream_t stream) {
  const float* act  = (const float*)d_in[0];
  const float* mask = (const float*)d_in[1];
  const float* nsc  = (const float*)d_in[2];
  const float* nbi  = (const float*)d_in[3];
  const float* w_l  = (const float*)d_in[4];
  const float* b_l  = (const float*)d_in[5];
  const float* w_r  = (const float*)d_in[6];
  const float* b_r  = (const float*)d_in[7];
  const float* w_lg = (const float*)d_in[8];
  const float* b_lg = (const float*)d_in[9];
  const float* w_rg = (const float*)d_in[10];
  const float* b_rg = (const float*)d_in[11];
  const float* fns  = (const float*)d_in[12];
  const float* fnb  = (const float*)d_in[13];
  const float* w_o  = (const float*)d_in[14];
  const float* b_o  = (const float*)d_in[15];
  const float* w_fg = (const float*)d_in[16];
  const float* b_fg = (const float*)d_in[17];
  float* outp = (float*)d_out;

  char* ws = (char*)d_ws;
  unsigned short* xbf    = (unsigned short*)ws;                         // 64MB bf16 x (chunk-swizzled)
  unsigned short* leftT  = (unsigned short*)(ws + ((size_t)64 << 20));  // 64MB [c][i*512+k]
  unsigned short* rightT = (unsigned short*)(ws + ((size_t)128 << 20)); // 64MB
  unsigned short* eout   = (unsigned short*)(ws + ((size_t)192 << 20)); // 64MB bf16 [c][i*512+j]
  unsigned short* wtall  = (unsigned short*)(ws + ((size_t)320 << 20)); // 192KB

  k_ln<<<NPOS/64 + 6, 256, 0, stream>>>(act, nsc, nbi,
                                        w_l, w_lg, w_r, w_rg, w_o, w_fg,
                                        xbf, wtall);
  k_proj<<<1024, 512, 0, stream>>>(xbf, mask, b_l, b_lg, b_r, b_rg, wtall, leftT, rightT);
  k_einsum<<<2048, 256, 0, stream>>>(leftT, rightT, eout);
  k_stageC<<<512, 512, 0, stream>>>(eout, xbf, wtall, fns, fnb, b_o, b_fg, outp);
}

// Round 16
// 232.228 us; speedup vs baseline: 1.5656x; 1.0194x over previous
//
#include <hip/hip_runtime.h>
#include <hip/hip_bf16.h>
#include <stdint.h>

#define LDIM 512
#define CDIM 128
#define NPOS (LDIM*LDIM)   // 262144 positions

typedef __attribute__((ext_vector_type(8))) short bf16x8;
typedef __attribute__((ext_vector_type(4))) float f32x4;

__device__ __forceinline__ unsigned short f2bf(float f) {
  union { __hip_bfloat16 h; unsigned short u; } cv;
  cv.h = __float2bfloat16(f);
  return cv.u;
}

__device__ __forceinline__ float bf2f(unsigned short u) {
  union { unsigned int i; float f; } cv; cv.i = ((unsigned int)u) << 16; return cv.f;
}

__device__ __forceinline__ float sigm(float x) { return 1.0f / (1.0f + __expf(-x)); }

// async global->LDS, 16B per lane. LDS dest must be wave-uniform; HW adds lane*16.
__device__ __forceinline__ void gl_lds16(const unsigned short* g, unsigned short* l) {
  __builtin_amdgcn_global_load_lds(
      (const __attribute__((address_space(1))) unsigned int*)g,
      (__attribute__((address_space(3))) unsigned int*)l, 16, 0, 0);
}

// ---------------------------------------------------------------------------
// K_LN (+prep): blocks [0,4096) = streaming LayerNorm; blocks [4096,4102) =
// weight transpose/convert (one 128x128 matrix each).
// LN: act (f32 [pos][128]) -> xbf (bf16, chunk-swizzled: chunk ch of row pos
// at slot ch^(pos&7)). Lane qq owns chunks {qq,4+qq,8+qq,12+qq} -> full-line
// stores. Prep: Wt[n][k] bf16, chunk s at slot s^(n&7).
// Slots: 0=w_left 1=w_lgate 2=w_right 3=w_rgate 4=w_out 5=w_fgate
// ---------------------------------------------------------------------------
__global__ __launch_bounds__(256,8) void k_ln(
    const float* __restrict__ act,
    const float* __restrict__ nscale, const float* __restrict__ nbias,
    const float* w0, const float* w1, const float* w2,
    const float* w3, const float* w4, const float* w5,
    unsigned short* __restrict__ xbf,
    unsigned short* __restrict__ wtall) {
  const int t = threadIdx.x;
  if (blockIdx.x >= NPOS/64) {   // ---- prep path (6 blocks)
    __shared__ float tmp[CDIM*CDIM];   // 64KB
    const int wi = blockIdx.x - NPOS/64;
    const float* w = (wi==0)?w0:(wi==1)?w1:(wi==2)?w2:(wi==3)?w3:(wi==4)?w4:w5;
    #pragma unroll
    for (int m = 0; m < 16; ++m)
      ((float4*)tmp)[m*256 + t] = ((const float4*)w)[m*256 + t];
    __syncthreads();
    unsigned short* out = wtall + (size_t)wi * (CDIM*CDIM);
    #pragma unroll
    for (int m = 0; m < 8; ++m) {
      int oc = m*256 + t;            // output 16B chunk index (n*16 + sc)
      int n = oc >> 4, sc = oc & 15;
      int s = sc ^ (n & 7);          // data chunk that lands in slot sc
      union { unsigned short u[8]; uint4 v; } pk;
      #pragma unroll
      for (int e = 0; e < 8; ++e) pk.u[e] = f2bf(tmp[(s*8 + e)*CDIM + n]);
      *(uint4*)(out + (size_t)oc*8) = pk.v;
    }
    return;
  }

  const int pos = blockIdx.x * 64 + (t >> 2), qq = t & 3;
  const int s = pos & 7;

  float4 av[8];
  const float4* ap = (const float4*)(act + (size_t)pos*CDIM);
  #pragma unroll
  for (int cc = 0; cc < 4; ++cc) {
    int ch = cc*4 + qq;
    av[cc*2]     = ap[ch*2];
    av[cc*2 + 1] = ap[ch*2 + 1];
  }

  float sm = 0.f, s2 = 0.f;
  #pragma unroll
  for (int j = 0; j < 8; ++j) {
    float4 v = av[j];
    sm += v.x + v.y + v.z + v.w;
    s2 += v.x*v.x + v.y*v.y + v.z*v.z + v.w*v.w;
  }
  sm += __shfl_xor(sm, 1); s2 += __shfl_xor(s2, 1);
  sm += __shfl_xor(sm, 2); s2 += __shfl_xor(s2, 2);
  float mu = sm * 0.0078125f;
  float rs = rsqrtf(fmaxf(s2 * 0.0078125f - mu*mu, 0.f) + 1e-5f);

  unsigned short* xp = xbf + (size_t)pos * CDIM;
  #pragma unroll
  for (int cc = 0; cc < 4; ++cc) {
    int ch = cc*4 + qq;
    union { unsigned short u[8]; uint4 v; } pk;
    #pragma unroll
    for (int e2 = 0; e2 < 2; ++e2) {
      float4 v = av[cc*2 + e2];
      float4 fs = ((const float4*)nscale)[ch*2 + e2];
      float4 fb = ((const float4*)nbias)[ch*2 + e2];
      int b = e2*4;
      pk.u[b+0] = f2bf((v.x - mu)*rs*fs.x + fb.x);
      pk.u[b+1] = f2bf((v.y - mu)*rs*fs.y + fb.y);
      pk.u[b+2] = f2bf((v.z - mu)*rs*fs.z + fb.z);
      pk.u[b+3] = f2bf((v.w - mu)*rs*fs.w + fb.w);
    }
    int slot = ch ^ s;
    *(uint4*)(xp + slot*8) = pk.v;
  }
}

// ---------------------------------------------------------------------------
// K_PROJ: x @ {w_value, w_gate} with gating+mask, one SIDE per block:
// blocks [0,512) -> left (w_left,w_lgate), blocks [512,1024) -> right.
// 512 thr (8 waves), 2 weight matrices staged ONCE (64KB) -> 80KB LDS ->
// 2 blocks/CU. Loop over 8 tiles of 64 positions; x-tile relayed
// global->reg->LDS. Relay writes are CONTIGUOUS half-tiles (t*8 shorts =
// 16B lane stride -> bank-conflict-free; layout identical to linear copy).
// Bias (bvn/bgn per nf) and mask-row scalar (mi) hoisted: block-invariant.
// 2 barriers per tile.
// ---------------------------------------------------------------------------
__global__ __launch_bounds__(512,4) void k_proj(
    const unsigned short* __restrict__ xbf,
    const float* __restrict__ mask,
    const float* __restrict__ b_left, const float* __restrict__ b_lgate,
    const float* __restrict__ b_right, const float* __restrict__ b_rgate,
    const unsigned short* __restrict__ wtall,
    unsigned short* __restrict__ leftT,
    unsigned short* __restrict__ rightT) {
  __shared__ unsigned short WB[2*128*128];   // 64KB: value, gate
  __shared__ unsigned short xs[64*128];      // 16KB x tile (chunk-swizzled)
  const int t = threadIdx.x, wave = t >> 6, lane = t & 63;
  const int fr = lane & 15, kg = lane >> 4;
  const int rg = wave >> 1, cg = wave & 1;
  const int ar = rg*16 + fr;
  const int rbase = rg*16 + kg*4;

  const int side = blockIdx.x >> 9;
  const unsigned short* W = wtall + (size_t)side * 2 * 16384;
  const float* bv = side ? b_right : b_left;
  const float* bg = side ? b_rgate : b_lgate;
  unsigned short* dst = side ? rightT : leftT;

  // stage both weights once (4096 chunks / 512 thr = 8 per thread)
  #pragma unroll
  for (int m = 0; m < 8; ++m) {
    int qb = m*512 + wave*64;
    gl_lds16(W + (size_t)(qb + lane)*8, WB + qb*8);
  }

  const int tile0 = (blockIdx.x & 511) * 8;
  // hoisted block-invariants: bias pairs (n is tile-invariant) + mask row scalar
  float bvn[4], bgn[4];
  #pragma unroll
  for (int nf = 0; nf < 4; ++nf) {
    int n = cg*64 + nf*16 + fr;
    bvn[nf] = bv[n]; bgn[nf] = bg[n];
  }
  const float mi = mask[(tile0 * 64) >> 9];

  // prefetch x tile 0 into regs (two contiguous half-tiles, 16B per thread each)
  uint4 xr0, xr1;
  {
    const uint4* src = (const uint4*)(xbf + (size_t)tile0*64*CDIM);
    xr0 = src[t]; xr1 = src[512 + t];
  }

  for (int tt = 0; tt < 8; ++tt) {
    const int p0 = (tile0 + tt) * 64;
    // x tile -> LDS: contiguous 16B/thread writes (conflict-free, same layout)
    *(uint4*)(xs + t*8)        = xr0;
    *(uint4*)(xs + 4096 + t*8) = xr1;
    __syncthreads();   // xs ready; (first iter: weights drained too)

    if (tt < 7) {      // issue next tile's loads; land during MFMA phase
      const uint4* src = (const uint4*)(xbf + (size_t)(p0 + 64)*CDIM);
      xr0 = src[t]; xr1 = src[512 + t];
    }

    // A fragments
    bf16x8 afr[4];
    #pragma unroll
    for (int ks = 0; ks < 4; ++ks)
      afr[ks] = *(const bf16x8*)(xs + ar*128 + (((ks*4 + kg) ^ (ar & 7)) * 8));

    // 32 MFMAs: 2 weights x 4 col-frags x 4 k-steps
    f32x4 acc[2][4];
    const f32x4 fz = {0.f,0.f,0.f,0.f};
    #pragma unroll
    for (int wi = 0; wi < 2; ++wi) {
      #pragma unroll
      for (int nf = 0; nf < 4; ++nf) {
        acc[wi][nf] = fz;
        int n = cg*64 + nf*16 + fr;
        const unsigned short* Wp = WB + wi*16384 + n*128;
        #pragma unroll
        for (int ks = 0; ks < 4; ++ks) {
          bf16x8 b = *(const bf16x8*)(Wp + (((ks*4 + kg) ^ (n & 7)) * 8));
          acc[wi][nf] = __builtin_amdgcn_mfma_f32_16x16x32_bf16(afr[ks], b, acc[wi][nf], 0,0,0);
        }
      }
    }

    // epilogue: gate + mask; pack 4 consecutive positions -> 8B stores
    float pm[4];
    #pragma unroll
    for (int jj = 0; jj < 4; ++jj)
      pm[jj] = mi * mask[(p0 & 511) + rbase + jj];
    #pragma unroll
    for (int nf = 0; nf < 4; ++nf) {
      int n = cg*64 + nf*16 + fr;
      union { unsigned short u[4]; uint2 v; } pl;
      #pragma unroll
      for (int jj = 0; jj < 4; ++jj)
        pl.u[jj] = f2bf((acc[0][nf][jj] + bvn[nf]) * pm[jj] * sigm(acc[1][nf][jj] + bgn[nf]));
      *(uint2*)(dst + (size_t)n*NPOS + p0 + rbase) = pl.v;
    }
    if (tt < 7) __syncthreads();   // all waves done reading xs
  }
}

// ---------------------------------------------------------------------------
// KB: einsum. Per block: one c-plane, 128x128 output tile, K=512, double-buffered.
// out[c][i][j] = sum_k L[c][i][k] * R[c][j][k]. Output bf16 via LDS bounce.
// ---------------------------------------------------------------------------
__global__ __launch_bounds__(256,2) void k_einsum(
    const unsigned short* __restrict__ leftT,
    const unsigned short* __restrict__ rightT,
    unsigned short* __restrict__ eout) {
  __shared__ unsigned short At[2][128*64];   // 2x16KB (also output bounce)
  __shared__ unsigned short Bt[2][128*64];
  const int t = threadIdx.x, wave = t >> 6, lane = t & 63;
  // XCD-chunked swizzle: 16 tiles of one c-plane stay on one XCD (2048 = 8*256)
  int fl = (blockIdx.x & 7) * 256 + (blockIdx.x >> 3);
  const int c = fl >> 4;
  const int i0 = ((fl >> 2) & 3) * 128, j0 = (fl & 3) * 128;
  const unsigned short* Lp = leftT + (size_t)c * NPOS;
  const unsigned short* Rp = rightT + (size_t)c * NPOS;
  const int wrow = (wave >> 1) * 64, wcol = (wave & 1) * 64;
  const int kg = lane >> 4, fr = lane & 15;

  f32x4 acc[4][4];
  const f32x4 fz = {0.f,0.f,0.f,0.f};
  #pragma unroll
  for (int a = 0; a < 4; ++a)
    #pragma unroll
    for (int b = 0; b < 4; ++b) acc[a][b] = fz;

  #define STAGE(buf, kt) do {                                              \
    _Pragma("unroll")                                                      \
    for (int m = 0; m < 4; ++m) {                                          \
      int qb = m*256 + wave*64;                                            \
      int qq = qb + lane;                                                  \
      int r = qq >> 3;                                                     \
      int kk = (qq & 7) ^ (r & 7);                                         \
      gl_lds16(Lp + ((size_t)(i0 + r) << 9) + (kt)*64 + kk*8, At[buf] + qb*8); \
      gl_lds16(Rp + ((size_t)(j0 + r) << 9) + (kt)*64 + kk*8, Bt[buf] + qb*8); \
    }                                                                      \
  } while (0)

  STAGE(0, 0);
  __syncthreads();
  int cur = 0;
  for (int kt = 0; kt < 8; ++kt) {
    if (kt < 7) STAGE(cur ^ 1, kt + 1);
    #pragma unroll
    for (int ks = 0; ks < 2; ++ks) {
      bf16x8 af[4], bfr[4];
      #pragma unroll
      for (int mf = 0; mf < 4; ++mf) {
        int r = wrow + mf*16 + fr;
        af[mf] = *(const bf16x8*)(At[cur] + r*64 + (((ks*4 + kg) ^ (r & 7)) * 8));
      }
      #pragma unroll
      for (int nf = 0; nf < 4; ++nf) {
        int r = wcol + nf*16 + fr;
        bfr[nf] = *(const bf16x8*)(Bt[cur] + r*64 + (((ks*4 + kg) ^ (r & 7)) * 8));
      }
      #pragma unroll
      for (int mf = 0; mf < 4; ++mf)
        #pragma unroll
        for (int nf = 0; nf < 4; ++nf)
          acc[mf][nf] = __builtin_amdgcn_mfma_f32_16x16x32_bf16(af[mf], bfr[nf], acc[mf][nf], 0,0,0);
    }
    __syncthreads();   // drains vmcnt (next tile staged) + all reads of cur done
    cur ^= 1;
  }
  #undef STAGE

  // epilogue: acc -> bounce (bank-swizzled [ri][ci]) -> full-line bf16 stores
  unsigned short* bounce = &At[0][0];   // 32KB
  const int rb = kg << 2;
  #pragma unroll
  for (int mf = 0; mf < 4; ++mf) {
    #pragma unroll
    for (int nf = 0; nf < 4; ++nf) {
      #pragma unroll
      for (int jj = 0; jj < 4; ++jj) {
        int ri = wrow + mf*16 + rb + jj;
        int ci = wcol + nf*16 + fr;
        bounce[ri*128 + (((ci >> 3) ^ (ri & 7)) << 3) + (ci & 7)] = f2bf(acc[mf][nf][jj]);
      }
    }
  }
  __syncthreads();
  unsigned short* op = eout + (size_t)c * NPOS;
  #pragma unroll
  for (int rr = 0; rr < 8; ++rr) {
    int flat = rr*256 + t;
    int row = flat >> 4, ch = flat & 15;
    uint4 v = *(const uint4*)(bounce + row*128 + ((ch ^ (row & 7)) << 3));
    *(uint4*)(op + (size_t)(i0 + row)*LDIM + j0 + ch*8) = v;
  }
}

// ---------------------------------------------------------------------------
// KC: 512 thr, 8 tiles of 64 positions per block (512 blocks). Both weights
// staged ONCE (64KB). x/eout tiles double-buffered via reg-relay (T14:
// issue-early after barrier A, write-late into alternate buffer). 3 barriers
// per tile. LN over c via 8-wave psum; ytile reuses es[cur] (XOR-swizzled,
// bank-conflict-free). LDS 132KB -> 1 block/CU (8 waves).
// ---------------------------------------------------------------------------
__global__ __launch_bounds__(512,2) void k_stageC(
    const unsigned short* __restrict__ eout,
    const unsigned short* __restrict__ xbf,
    const unsigned short* __restrict__ wtall,
    const float* __restrict__ fns, const float* __restrict__ fnb,
    const float* __restrict__ b_out, const float* __restrict__ b_fg,
    float* __restrict__ outp) {
  __shared__ unsigned short WB[2][128*128];  // 64KB: WB0=w_fgate, WB1=w_out
  __shared__ unsigned short xs[2][64*128];   // 32KB x tiles (chunk-swizzled)
  __shared__ unsigned short es[2][64*128];   // 32KB eout tiles [c][pos] -> ytile [pos][c]
  __shared__ float psum[2][8][64];           // 4KB partial LN sums
  const int t = threadIdx.x, wave = t >> 6, lane = t & 63;
  const int fr = lane & 15, kg = lane >> 4;
  const int rg = wave >> 1, cg = wave & 1;
  const int ar = rg*16 + fr;
  const int rbase = rg*16 + kg*4;

  // stage both weights once (2048 chunks each / 512 thr = 4 per thread per mat)
  #pragma unroll
  for (int m = 0; m < 4; ++m) {
    int qb = m*512 + wave*64;
    gl_lds16(wtall + 5*16384 + (size_t)(qb + lane)*8, WB[0] + qb*8);  // w_fgate
    gl_lds16(wtall + 4*16384 + (size_t)(qb + lane)*8, WB[1] + qb*8);  // w_out
  }

  const int tile0 = blockIdx.x * 8;
  uint4 xr0, xr1, er0, er1;
  {
    const uint4* xsrc = (const uint4*)(xbf + (size_t)tile0*64*CDIM);
    xr0 = xsrc[t]; xr1 = xsrc[512 + t];
    const unsigned short* eb = eout + (size_t)tile0*64;
    er0 = *(const uint4*)(eb + (size_t)(t >> 3)*NPOS + (t & 7)*8);          // c = t>>3
    er1 = *(const uint4*)(eb + (size_t)(64 + (t >> 3))*NPOS + (t & 7)*8);   // c = 64+t>>3
  }
  *(uint4*)(xs[0] + t*8) = xr0; *(uint4*)(xs[0] + 4096 + t*8) = xr1;
  *(uint4*)(es[0] + t*8) = er0; *(uint4*)(es[0] + 4096 + t*8) = er1;

  int cur = 0;
  const f32x4 fz = {0.f,0.f,0.f,0.f};
  for (int tt = 0; tt < 8; ++tt) {
    const int p0 = (tile0 + tt) * 64;
    __syncthreads();   // A: cur tile visible (first iter: weights drained too)

    if (tt < 7) {      // T14 issue-early: next tile's loads fly during compute
      const uint4* xsrc = (const uint4*)(xbf + (size_t)(p0 + 64)*CDIM);
      xr0 = xsrc[t]; xr1 = xsrc[512 + t];
      const unsigned short* eb = eout + (size_t)(p0 + 64);
      er0 = *(const uint4*)(eb + (size_t)(t >> 3)*NPOS + (t & 7)*8);
      er1 = *(const uint4*)(eb + (size_t)(64 + (t >> 3))*NPOS + (t & 7)*8);
    }

    // ---- LN over c: wave owns c=[wave*16,+16), lane = pos (conflict-free)
    float ev[16];
    #pragma unroll
    for (int j = 0; j < 16; ++j)
      ev[j] = bf2f(es[cur][(wave*16 + j)*64 + lane]);
    float s = 0.f, s2 = 0.f;
    #pragma unroll
    for (int j = 0; j < 16; ++j) { s += ev[j]; s2 += ev[j]*ev[j]; }
    psum[0][wave][lane] = s; psum[1][wave][lane] = s2;
    __syncthreads();   // B: partials ready (all es reads done)
    float st = 0.f, s2t = 0.f;
    #pragma unroll
    for (int w = 0; w < 8; ++w) { st += psum[0][w][lane]; s2t += psum[1][w][lane]; }
    float mu = st * 0.0078125f;
    float rs = rsqrtf(fmaxf(s2t * 0.0078125f - mu*mu, 0.f) + 1e-5f);

    // x A-fragments + fgate matmul
    bf16x8 afr[4];
    #pragma unroll
    for (int ks = 0; ks < 4; ++ks)
      afr[ks] = *(const bf16x8*)(xs[cur] + ar*128 + (((ks*4 + kg) ^ (ar & 7)) * 8));

    f32x4 accG[4], accY[4];
    #pragma unroll
    for (int nf = 0; nf < 4; ++nf) {
      accG[nf] = fz;
      int n = cg*64 + nf*16 + fr;
      #pragma unroll
      for (int ks = 0; ks < 4; ++ks) {
        bf16x8 b = *(const bf16x8*)(WB[0] + n*128 + (((ks*4 + kg) ^ (n & 7)) * 8));
        accG[nf] = __builtin_amdgcn_mfma_f32_16x16x32_bf16(afr[ks], b, accG[nf], 0,0,0);
      }
    }

    // normalized ytile -> es[cur] as [pos=lane][c] chunk-swizzled
    #pragma unroll
    for (int k = 0; k < 2; ++k) {
      union { unsigned short u[8]; uint4 v; } pk;
      #pragma unroll
      for (int e4 = 0; e4 < 2; ++e4) {
        float4 fsv = ((const float4*)fns)[wave*4 + k*2 + e4];
        float4 fbv = ((const float4*)fnb)[wave*4 + k*2 + e4];
        int j = k*8 + e4*4;
        pk.u[e4*4+0] = f2bf((ev[j+0]-mu)*rs*fsv.x + fbv.x);
        pk.u[e4*4+1] = f2bf((ev[j+1]-mu)*rs*fsv.y + fbv.y);
        pk.u[e4*4+2] = f2bf((ev[j+2]-mu)*rs*fsv.z + fbv.z);
        pk.u[e4*4+3] = f2bf((ev[j+3]-mu)*rs*fsv.w + fbv.w);
      }
      int ch = wave*2 + k;
      int slot = ch ^ (lane & 7);
      *(uint4*)(es[cur] + lane*128 + slot*8) = pk.v;
    }
    __syncthreads();   // C: ytile visible

    bf16x8 yfr[4];
    #pragma unroll
    for (int ks = 0; ks < 4; ++ks)
      yfr[ks] = *(const bf16x8*)(es[cur] + ar*128 + (((ks*4 + kg) ^ (ar & 7)) * 8));
    #pragma unroll
    for (int nf = 0; nf < 4; ++nf) {
      accY[nf] = fz;
      int n = cg*64 + nf*16 + fr;
      #pragma unroll
      for (int ks = 0; ks < 4; ++ks) {
        bf16x8 b = *(const bf16x8*)(WB[1] + n*128 + (((ks*4 + kg) ^ (n & 7)) * 8));
        accY[nf] = __builtin_amdgcn_mfma_f32_16x16x32_bf16(yfr[ks], b, accY[nf], 0,0,0);
      }
    }

    // epilogue: gate + store f32 (16 lanes x 4B = full 64B lines)
    #pragma unroll
    for (int nf = 0; nf < 4; ++nf) {
      int n = cg*64 + nf*16 + fr;
      float bo = b_out[n], bfg = b_fg[n];
      #pragma unroll
      for (int jj = 0; jj < 4; ++jj) {
        float val = (accY[nf][jj] + bo) * sigm(accG[nf][jj] + bfg);
        outp[(size_t)(p0 + rbase + jj)*CDIM + n] = val;
      }
    }

    if (tt < 7) {   // T14 write-late into alternate buffer
      *(uint4*)(xs[cur^1] + t*8) = xr0; *(uint4*)(xs[cur^1] + 4096 + t*8) = xr1;
      *(uint4*)(es[cur^1] + t*8) = er0; *(uint4*)(es[cur^1] + 4096 + t*8) = er1;
      cur ^= 1;
    }
  }
}

// ---------------------------------------------------------------------------
extern "C" void kernel_launch(void* const* d_in, const int* in_sizes, int n_in,
                              void* d_out, int out_size, void* d_ws, size_t ws_size,
                              hipStream_t stream) {
  const float* act  = (const float*)d_in[0];
  const float* mask = (const float*)d_in[1];
  const float* nsc  = (const float*)d_in[2];
  const float* nbi  = (const float*)d_in[3];
  const float* w_l  = (const float*)d_in[4];
  const float* b_l  = (const float*)d_in[5];
  const float* w_r  = (const float*)d_in[6];
  const float* b_r  = (const float*)d_in[7];
  const float* w_lg = (const float*)d_in[8];
  const float* b_lg = (const float*)d_in[9];
  const float* w_rg = (const float*)d_in[10];
  const float* b_rg = (const float*)d_in[11];
  const float* fns  = (const float*)d_in[12];
  const float* fnb  = (const float*)d_in[13];
  const float* w_o  = (const float*)d_in[14];
  const float* b_o  = (const float*)d_in[15];
  const float* w_fg = (const float*)d_in[16];
  const float* b_fg = (const float*)d_in[17];
  float* outp = (float*)d_out;

  char* ws = (char*)d_ws;
  unsigned short* xbf    = (unsigned short*)ws;                         // 64MB bf16 x (chunk-swizzled)
  unsigned short* leftT  = (unsigned short*)(ws + ((size_t)64 << 20));  // 64MB [c][i*512+k]
  unsigned short* rightT = (unsigned short*)(ws + ((size_t)128 << 20)); // 64MB
  unsigned short* eout   = (unsigned short*)(ws + ((size_t)192 << 20)); // 64MB bf16 [c][i*512+j]
  unsigned short* wtall  = (unsigned short*)(ws + ((size_t)320 << 20)); // 192KB

  k_ln<<<NPOS/64 + 6, 256, 0, stream>>>(act, nsc, nbi,
                                        w_l, w_lg, w_r, w_rg, w_o, w_fg,
                                        xbf, wtall);
  k_proj<<<1024, 512, 0, stream>>>(xbf, mask, b_l, b_lg, b_r, b_rg, wtall, leftT, rightT);
  k_einsum<<<2048, 256, 0, stream>>>(leftT, rightT, eout);
  k_stageC<<<512, 512, 0, stream>>>(eout, xbf, wtall, fns, fnb, b_o, b_fg, outp);
}